// Round 1
// baseline (3186.294 us; speedup 1.0000x reference)
//
#include <hip/hip_runtime.h>
#include <math.h>

// ---------------------------------------------------------------------------
// Types for MFMA
typedef __bf16 bf16x8 __attribute__((ext_vector_type(8)));
typedef short s16x8 __attribute__((ext_vector_type(8)));
typedef float f32x4 __attribute__((ext_vector_type(4)));

__device__ inline unsigned short f2bf(float f) {
  union { float f; unsigned u; } v; v.f = f;
  unsigned u = v.u;
  unsigned r = u + 0x7fffu + ((u >> 16) & 1u);
  return (unsigned short)(r >> 16);
}

// ---------------------------------------------------------------------------
// GEMM: C[M,N] = A[M,K] @ B[N,K]^T   (fp32 in/out, bf16 MFMA inside)
// M multiple of 128, K multiple of 32. N arbitrary (guarded).
#define GT_M 128
#define GT_N 128
#define GT_K 32
#define LDT 40  // padded LDS row stride in elements (bf16)

__global__ __launch_bounds__(256, 2)
void gemm_bt(const float* __restrict__ A, const float* __restrict__ B,
             float* __restrict__ Cmat, int M, int N, int K) {
  __shared__ __align__(16) unsigned short As[GT_M * LDT];
  __shared__ __align__(16) unsigned short Bs[GT_N * LDT];
  const int tid = threadIdx.x;
  const int tm0 = blockIdx.y * GT_M;
  const int tn0 = blockIdx.x * GT_N;
  const int wave = tid >> 6;
  const int lane = tid & 63;
  const int wm = (wave >> 1) * 64;
  const int wn = (wave & 1) * 64;
  const int frow = lane & 15;
  const int fk = (lane >> 4) * 8;

  f32x4 acc[4][4];
  f32x4 zero = {0.f, 0.f, 0.f, 0.f};
#pragma unroll
  for (int i = 0; i < 4; ++i)
#pragma unroll
    for (int j = 0; j < 4; ++j) acc[i][j] = zero;

  for (int kt = 0; kt < K; kt += GT_K) {
#pragma unroll
    for (int i = 0; i < 4; ++i) {
      int f = tid + i * 256;
      int row = f >> 3;
      int c4 = (f & 7) << 2;
      float4 v = *(const float4*)(A + (size_t)(tm0 + row) * K + kt + c4);
      unsigned short* dst = &As[row * LDT + c4];
      dst[0] = f2bf(v.x); dst[1] = f2bf(v.y); dst[2] = f2bf(v.z); dst[3] = f2bf(v.w);
    }
#pragma unroll
    for (int i = 0; i < 4; ++i) {
      int f = tid + i * 256;
      int row = f >> 3;
      int c4 = (f & 7) << 2;
      int gn = tn0 + row;
      float4 v;
      if (gn < N) v = *(const float4*)(B + (size_t)gn * K + kt + c4);
      else { v.x = 0.f; v.y = 0.f; v.z = 0.f; v.w = 0.f; }
      unsigned short* dst = &Bs[row * LDT + c4];
      dst[0] = f2bf(v.x); dst[1] = f2bf(v.y); dst[2] = f2bf(v.z); dst[3] = f2bf(v.w);
    }
    __syncthreads();
    bf16x8 af[4], bfr[4];
#pragma unroll
    for (int i = 0; i < 4; ++i) {
      s16x8 raw = *(const s16x8*)&As[(wm + i * 16 + frow) * LDT + fk];
      af[i] = __builtin_bit_cast(bf16x8, raw);
    }
#pragma unroll
    for (int j = 0; j < 4; ++j) {
      s16x8 raw = *(const s16x8*)&Bs[(wn + j * 16 + frow) * LDT + fk];
      bfr[j] = __builtin_bit_cast(bf16x8, raw);
    }
#pragma unroll
    for (int i = 0; i < 4; ++i)
#pragma unroll
      for (int j = 0; j < 4; ++j)
        acc[i][j] = __builtin_amdgcn_mfma_f32_16x16x32_bf16(af[i], bfr[j], acc[i][j], 0, 0, 0);
    __syncthreads();
  }
  const int ccol = lane & 15;
  const int crow = (lane >> 4) * 4;
#pragma unroll
  for (int i = 0; i < 4; ++i) {
#pragma unroll
    for (int j = 0; j < 4; ++j) {
      int gn = tn0 + wn + j * 16 + ccol;
      if (gn < N) {
        size_t base = (size_t)(tm0 + wm + i * 16 + crow) * N + gn;
#pragma unroll
        for (int r = 0; r < 4; ++r) Cmat[base + (size_t)r * N] = acc[i][j][r];
      }
    }
  }
}

// ---------------------------------------------------------------------------
// Block reduce (256 threads)
__device__ inline float block_reduce_sum_256(float v) {
  __shared__ float red[4];
  int lane = threadIdx.x & 63, wave = threadIdx.x >> 6;
#pragma unroll
  for (int m = 32; m > 0; m >>= 1) v += __shfl_xor(v, m, 64);
  if (lane == 0) red[wave] = v;
  __syncthreads();
  return red[0] + red[1] + red[2] + red[3];
}

// rmsnorm over C=2048, one block per row, 8 elems/thread in regs
__global__ __launch_bounds__(256)
void rmsnorm2048_k(const float* __restrict__ x, const float* __restrict__ w,
                   float* __restrict__ y) {
  const int C = 2048;
  const int row = blockIdx.x;
  const int t = threadIdx.x;
  const float4* xr = (const float4*)(x + (size_t)row * C);
  float4 v0 = xr[t];
  float4 v1 = xr[t + 256];
  float ss = v0.x * v0.x + v0.y * v0.y + v0.z * v0.z + v0.w * v0.w +
             v1.x * v1.x + v1.y * v1.y + v1.z * v1.z + v1.w * v1.w;
  float tot = block_reduce_sum_256(ss);
  float sc = rsqrtf(tot * (1.0f / C) + 1e-6f);
  const float4* wr = (const float4*)w;
  float4 w0 = wr[t], w1 = wr[t + 256];
  float4* yr = (float4*)(y + (size_t)row * C);
  float4 o0, o1;
  o0.x = v0.x * sc * w0.x; o0.y = v0.y * sc * w0.y;
  o0.z = v0.z * sc * w0.z; o0.w = v0.w * sc * w0.w;
  o1.x = v1.x * sc * w1.x; o1.y = v1.y * sc * w1.y;
  o1.z = v1.z * sc * w1.z; o1.w = v1.w * sc * w1.w;
  yr[t] = o0; yr[t + 256] = o1;
}

// residual = a + b (store), y = rmsnorm(residual)*w
__global__ __launch_bounds__(256)
void add_rmsnorm_k(const float* __restrict__ a, const float* __restrict__ b,
                   const float* __restrict__ w, float* __restrict__ resid,
                   float* __restrict__ y) {
  const int C = 2048;
  const int row = blockIdx.x;
  const int t = threadIdx.x;
  const float4* ar = (const float4*)(a + (size_t)row * C);
  const float4* br = (const float4*)(b + (size_t)row * C);
  float4 v0 = ar[t], v1 = ar[t + 256];
  float4 u0 = br[t], u1 = br[t + 256];
  v0.x += u0.x; v0.y += u0.y; v0.z += u0.z; v0.w += u0.w;
  v1.x += u1.x; v1.y += u1.y; v1.z += u1.z; v1.w += u1.w;
  float4* rr = (float4*)(resid + (size_t)row * C);
  rr[t] = v0; rr[t + 256] = v1;
  float ss = v0.x * v0.x + v0.y * v0.y + v0.z * v0.z + v0.w * v0.w +
             v1.x * v1.x + v1.y * v1.y + v1.z * v1.z + v1.w * v1.w;
  float tot = block_reduce_sum_256(ss);
  float sc = rsqrtf(tot * (1.0f / C) + 1e-6f);
  const float4* wr = (const float4*)w;
  float4 w0 = wr[t], w1 = wr[t + 256];
  float4* yr = (float4*)(y + (size_t)row * C);
  float4 o0, o1;
  o0.x = v0.x * sc * w0.x; o0.y = v0.y * sc * w0.y;
  o0.z = v0.z * sc * w0.z; o0.w = v0.w * sc * w0.w;
  o1.x = v1.x * sc * w1.x; o1.y = v1.y * sc * w1.y;
  o1.z = v1.z * sc * w1.z; o1.w = v1.w * sc * w1.w;
  yr[t] = o0; yr[t + 256] = o1;
}

// causal depthwise conv (K=4) + bias + silu ; input = proj[:, :Di] (ld=8192)
__global__ __launch_bounds__(256)
void conv_silu_k(const float* __restrict__ proj, const float* __restrict__ cw,
                 const float* __restrict__ cb, float* __restrict__ h) {
  const int Di = 4096, LD = 8192;
  int idx = blockIdx.x * 256 + threadIdx.x;
  int d = idx & (Di - 1);
  int l = idx >> 12;
  float4 w = *(const float4*)(cw + (size_t)d * 4);
  float acc = cb[d];
  int ls0 = l - 3;
  if (ls0 >= 0) acc += proj[(size_t)ls0 * LD + d] * w.x;
  if (ls0 + 1 >= 0) acc += proj[(size_t)(ls0 + 1) * LD + d] * w.y;
  if (ls0 + 2 >= 0) acc += proj[(size_t)(ls0 + 2) * LD + d] * w.z;
  acc += proj[(size_t)l * LD + d] * w.w;
  float sig = 1.0f / (1.0f + __expf(-acc));
  h[idx] = acc * sig;
}

// three rmsnorms over the 160-wide ssm rows: dt[128], B[16], C[16]
__global__ __launch_bounds__(64)
void ssm_norm_k(const float* __restrict__ ssm, const float* __restrict__ dtw,
                const float* __restrict__ bw, const float* __restrict__ cw,
                float* __restrict__ dtn, float* __restrict__ Bn,
                float* __restrict__ Cn) {
  int l = blockIdx.x;
  int lane = threadIdx.x;
  const float* r = ssm + (size_t)l * 160;
  float d0 = r[lane];
  float d1 = r[lane + 64];
  float bv = (lane < 16) ? r[128 + lane] : 0.f;
  float cv = (lane < 16) ? r[144 + lane] : 0.f;
  float sd = d0 * d0 + d1 * d1;
  float sb = bv * bv;
  float sc = cv * cv;
#pragma unroll
  for (int m = 32; m > 0; m >>= 1) {
    sd += __shfl_xor(sd, m, 64);
    sb += __shfl_xor(sb, m, 64);
    sc += __shfl_xor(sc, m, 64);
  }
  float scd = rsqrtf(sd * (1.f / 128.f) + 1e-6f);
  float scb = rsqrtf(sb * (1.f / 16.f) + 1e-6f);
  float scc = rsqrtf(sc * (1.f / 16.f) + 1e-6f);
  dtn[(size_t)l * 128 + lane] = d0 * scd * dtw[lane];
  dtn[(size_t)l * 128 + lane + 64] = d1 * scd * dtw[lane + 64];
  if (lane < 16) {
    Bn[(size_t)l * 16 + lane] = bv * scb * bw[lane];
    Cn[(size_t)l * 16 + lane] = cv * scc * cw[lane];
  }
}

// delta = softplus(delta_pre + bias[d]) in place
__global__ __launch_bounds__(256)
void softplus_bias_k(float* __restrict__ dp, const float* __restrict__ b) {
  const int Di = 4096;
  int i = blockIdx.x * 256 + threadIdx.x;
  int d = i & (Di - 1);
  float x = dp[i] + b[d];
  dp[i] = (x > 20.f) ? x : log1pf(__expf(x));
}

// selective scan: thread = (d,n); wave-reduce over n (16 lanes); fuse gate-silu
__global__ __launch_bounds__(256)
void scan_k(const float* __restrict__ delta, const float* __restrict__ h,
            const float* __restrict__ Bn, const float* __restrict__ Cn,
            const float* __restrict__ Amat, const float* __restrict__ Dw,
            const float* __restrict__ proj, float* __restrict__ y) {
  const int Di = 4096, L = 1024;
  int t = blockIdx.x * 256 + threadIdx.x;
  int d = t >> 4;
  int n = t & 15;
  float a = Amat[(size_t)d * 16 + n];
  float Dd = Dw[d];
  float s = 0.f;
  __shared__ float Bs[64 * 16];
  __shared__ float Cs[64 * 16];
  for (int lt = 0; lt < L; lt += 64) {
    __syncthreads();
    for (int i = threadIdx.x; i < 1024; i += 256) {
      Bs[i] = Bn[(size_t)lt * 16 + i];
      Cs[i] = Cn[(size_t)lt * 16 + i];
    }
    __syncthreads();
    for (int j = 0; j < 64; ++j) {
      int l = lt + j;
      float del = delta[(size_t)l * Di + d];
      float hv = h[(size_t)l * Di + d];
      float dA = __expf(del * a);
      s = dA * s + del * Bs[j * 16 + n] * hv;
      float p = s * Cs[j * 16 + n];
      p += __shfl_xor(p, 1, 64);
      p += __shfl_xor(p, 2, 64);
      p += __shfl_xor(p, 4, 64);
      p += __shfl_xor(p, 8, 64);
      if (n == 0) {
        float g = proj[(size_t)l * 8192 + 4096 + d];
        float yv = p + hv * Dd;
        y[(size_t)l * Di + d] = yv * g / (1.f + __expf(-g));
      }
    }
  }
}

// x3 = silu(gu[:, :F]) * gu[:, F:]
__global__ __launch_bounds__(256)
void swiglu_k(const float* __restrict__ gu, float* __restrict__ x3) {
  int idx = blockIdx.x * 256 + threadIdx.x;  // float4 index over L*F/4
  int l = idx >> 11;
  int c4 = (idx & 2047) << 2;
  float4 ga = *(const float4*)(gu + (size_t)l * 16384 + c4);
  float4 gb = *(const float4*)(gu + (size_t)l * 16384 + 8192 + c4);
  float4 o;
  o.x = ga.x / (1.f + __expf(-ga.x)) * gb.x;
  o.y = ga.y / (1.f + __expf(-ga.y)) * gb.y;
  o.z = ga.z / (1.f + __expf(-ga.z)) * gb.z;
  o.w = ga.w / (1.f + __expf(-ga.w)) * gb.w;
  *(float4*)(x3 + (size_t)l * 8192 + c4) = o;
}

// out += ff
__global__ __launch_bounds__(256)
void add_k(float* __restrict__ out, const float* __restrict__ ff) {
  int i = blockIdx.x * 256 + threadIdx.x;
  float4 a = ((const float4*)out)[i];
  float4 b = ((const float4*)ff)[i];
  a.x += b.x; a.y += b.y; a.z += b.z; a.w += b.w;
  ((float4*)out)[i] = a;
}

// ---------------------------------------------------------------------------
extern "C" void kernel_launch(void* const* d_in, const int* in_sizes, int n_in,
                              void* d_out, int out_size, void* d_ws, size_t ws_size,
                              hipStream_t stream) {
  const float* hidden      = (const float*)d_in[0];
  const float* in_ln_w     = (const float*)d_in[1];
  const float* pre_ff_ln_w = (const float*)d_in[2];
  const float* in_proj_w   = (const float*)d_in[3];
  const float* conv_w      = (const float*)d_in[4];
  const float* conv_b      = (const float*)d_in[5];
  const float* x_proj_w    = (const float*)d_in[6];
  const float* dt_ln_w     = (const float*)d_in[7];
  const float* b_ln_w      = (const float*)d_in[8];
  const float* c_ln_w      = (const float*)d_in[9];
  const float* dt_proj_w   = (const float*)d_in[10];
  const float* dt_proj_b   = (const float*)d_in[11];
  const float* Amat        = (const float*)d_in[12];
  const float* Dw          = (const float*)d_in[13];
  const float* out_proj_w  = (const float*)d_in[14];
  const float* gate_up_w   = (const float*)d_in[15];
  const float* down_w      = (const float*)d_in[16];
  float* out = (float*)d_out;
  float* ws = (float*)d_ws;

  const int L = 1024, H = 2048, Di = 4096, F = 8192;

  // workspace layout (floats)
  float* proj  = ws + 0;         // 8,388,608  (L x 8192)
  float* hbuf  = ws + 8388608;   // 4,194,304  (L x Di)
  float* dpre  = ws + 12582912;  // 4,194,304  (L x Di)
  float* xnorm = ws + 16777216;  // 2,097,152  (L x H) ; reused below
  float* ssm   = xnorm;          //   163,840  (L x 160)   [after gemm1]
  float* dtn   = xnorm + 163840; //   131,072  (L x 128)
  float* Bn    = xnorm + 294912; //    16,384  (L x 16)
  float* Cn    = xnorm + 311296; //    16,384  (L x 16)
  float* ybuf  = ws + 18874368;  // 4,194,304  (L x Di)
  float* mix   = ws + 23068672;  // 2,097,152  (L x H)
  float* x2    = ws + 25165824;  // 2,097,152  (L x H)
  float* ff    = ws + 27262976;  // 2,097,152  (L x H)
  float* gu    = ws + 0;         // 16,777,216 (L x 2F)  [reuse proj+h+dpre]
  float* x3    = ws + 18874368;  // 8,388,608  (L x F)   [reuse y+mix+x2]

  // 1. x_norm = rmsnorm(hidden, in_ln_w)
  rmsnorm2048_k<<<L, 256, 0, stream>>>(hidden, in_ln_w, xnorm);
  // 2. proj = x_norm @ in_proj_w.T   (1024 x 8192 x 2048)
  gemm_bt<<<dim3(2 * Di / 128, L / 128), 256, 0, stream>>>(xnorm, in_proj_w, proj, L, 2 * Di, H);
  // 3. h = silu(conv(proj[:, :Di]) + conv_b)
  conv_silu_k<<<(L * Di) / 256, 256, 0, stream>>>(proj, conv_w, conv_b, hbuf);
  // 4. ssm = h @ x_proj_w.T          (1024 x 160 x 4096)
  gemm_bt<<<dim3(2, L / 128), 256, 0, stream>>>(hbuf, x_proj_w, ssm, L, 160, Di);
  // 5. split rmsnorms
  ssm_norm_k<<<L, 64, 0, stream>>>(ssm, dt_ln_w, b_ln_w, c_ln_w, dtn, Bn, Cn);
  // 6. delta_pre = dtn @ dt_proj_w.T (1024 x 4096 x 128)
  gemm_bt<<<dim3(Di / 128, L / 128), 256, 0, stream>>>(dtn, dt_proj_w, dpre, L, Di, 128);
  // 7. delta = softplus(delta_pre + dt_proj_b)
  softplus_bias_k<<<(L * Di) / 256, 256, 0, stream>>>(dpre, dt_proj_b);
  // 8. selective scan + gate silu -> y
  scan_k<<<(Di * 16) / 256, 256, 0, stream>>>(dpre, hbuf, Bn, Cn, Amat, Dw, proj, ybuf);
  // 9. mix = y @ out_proj_w.T        (1024 x 2048 x 4096)
  gemm_bt<<<dim3(H / 128, L / 128), 256, 0, stream>>>(ybuf, out_proj_w, mix, L, H, Di);
  // 10. residual(out) = hidden + mix ; x2 = rmsnorm(residual, pre_ff_ln_w)
  add_rmsnorm_k<<<L, 256, 0, stream>>>(hidden, mix, pre_ff_ln_w, out, x2);
  // 11. gu = x2 @ gate_up_w.T        (1024 x 16384 x 2048)
  gemm_bt<<<dim3(2 * F / 128, L / 128), 256, 0, stream>>>(x2, gate_up_w, gu, L, 2 * F, H);
  // 12. x3 = silu(gu[:, :F]) * gu[:, F:]
  swiglu_k<<<(L * F / 4) / 256, 256, 0, stream>>>(gu, x3);
  // 13. ff = x3 @ down_w.T           (1024 x 2048 x 8192)
  gemm_bt<<<dim3(H / 128, L / 128), 256, 0, stream>>>(x3, down_w, ff, L, H, F);
  // 14. out += ff
  add_k<<<(L * H / 4) / 256, 256, 0, stream>>>(out, ff);
}

// Round 2
// 1655.202 us; speedup vs baseline: 1.9250x; 1.9250x over previous
//
#include <hip/hip_runtime.h>
#include <math.h>

typedef unsigned short u16;
typedef __bf16 bf16x8 __attribute__((ext_vector_type(8)));
typedef short s16x8 __attribute__((ext_vector_type(8)));
typedef short s16x4 __attribute__((ext_vector_type(4)));
typedef float f32x4 __attribute__((ext_vector_type(4)));

__device__ __forceinline__ u16 f2bf(float f) {
  union { float f; unsigned u; } v; v.f = f;
  unsigned u = v.u;
  unsigned r = u + 0x7fffu + ((u >> 16) & 1u);
  return (u16)(r >> 16);
}
__device__ __forceinline__ float bf2f(u16 h) {
  union { unsigned u; float f; } v; v.u = ((unsigned)h) << 16;
  return v.f;
}

__device__ __forceinline__ void gld_lds16(const u16* g, u16* l) {
  __builtin_amdgcn_global_load_lds(
      (const __attribute__((address_space(1))) unsigned int*)g,
      (__attribute__((address_space(3))) unsigned int*)l, 16, 0, 0);
}

// ---------------------------------------------------------------------------
// fp32 -> bf16 weight conversion, zero-pads [n_valid, n)
__global__ __launch_bounds__(256)
void f32_to_bf16_k(const float* __restrict__ src, u16* __restrict__ dst,
                   int n, int n_valid) {
  int i = (blockIdx.x * 256 + threadIdx.x) * 4;
  if (i >= n) return;
  s16x4 o;
  if (i + 3 < n_valid) {
    float4 v = *(const float4*)(src + i);
    o[0] = (short)f2bf(v.x); o[1] = (short)f2bf(v.y);
    o[2] = (short)f2bf(v.z); o[3] = (short)f2bf(v.w);
  } else {
    o[0] = 0; o[1] = 0; o[2] = 0; o[3] = 0;
  }
  *(s16x4*)(dst + i) = o;
}

// ---------------------------------------------------------------------------
// GEMM (m97 structure): C[M,N] = A[M,K](bf16) @ B[N,K](bf16)^T
// M,Nt multiples of 128; K multiple of 32. Nt = gridDim.x*128 (B zero-padded).
// MODE 0: C fp32.  MODE 1: Cb = bf16(silu(c)).  MODE 2: Cb = bf16(c*aux).
template <int MODE>
__global__ __launch_bounds__(256)
void gemm_bf16(const u16* __restrict__ A, const u16* __restrict__ B,
               float* __restrict__ C, u16* __restrict__ Cb,
               const u16* __restrict__ aux, int M, int Nc, int K) {
  __shared__ __align__(16) u16 As[128 * 32];
  __shared__ __align__(16) u16 Bs[128 * 32];
  const int tid = threadIdx.x;
  const int tm0 = blockIdx.y * 128;
  const int tn0 = blockIdx.x * 128;
  const int wave = tid >> 6;
  const int lane = tid & 63;
  const int wm = (wave >> 1) * 64;
  const int wn = (wave & 1) * 64;
  const int frow = lane & 15;
  const int fk = (lane >> 4) * 8;

  // staging: thread t covers tile elems [8t,8t+8) and [2048+8t, ...)
  const int r0 = tid >> 2;          // tile row 0..63
  const int c0 = (tid & 3) << 3;    // col 0,8,16,24
  const u16* gA = A + (size_t)(tm0 + r0) * K + c0;
  const u16* gB = B + (size_t)(tn0 + r0) * K + c0;
  const size_t half = (size_t)64 * K;
  u16* lA = &As[tid * 8];
  u16* lB = &Bs[tid * 8];

  f32x4 acc[4][4];
  f32x4 zero = {0.f, 0.f, 0.f, 0.f};
#pragma unroll
  for (int i = 0; i < 4; ++i)
#pragma unroll
    for (int j = 0; j < 4; ++j) acc[i][j] = zero;

  for (int kt = 0; kt < K; kt += 32) {
    __syncthreads();  // prior iter's ds_reads complete before overwrite
    gld_lds16(gA, lA);
    gld_lds16(gA + half, lA + 2048);
    gld_lds16(gB, lB);
    gld_lds16(gB + half, lB + 2048);
    gA += 32; gB += 32;
    __syncthreads();  // DMA drained (compiler emits vmcnt(0) before barrier)
    bf16x8 af[4], bfr[4];
#pragma unroll
    for (int i = 0; i < 4; ++i) {
      s16x8 raw = *(const s16x8*)&As[(wm + i * 16 + frow) * 32 + fk];
      af[i] = __builtin_bit_cast(bf16x8, raw);
    }
#pragma unroll
    for (int j = 0; j < 4; ++j) {
      s16x8 raw = *(const s16x8*)&Bs[(wn + j * 16 + frow) * 32 + fk];
      bfr[j] = __builtin_bit_cast(bf16x8, raw);
    }
#pragma unroll
    for (int i = 0; i < 4; ++i)
#pragma unroll
      for (int j = 0; j < 4; ++j)
        acc[i][j] = __builtin_amdgcn_mfma_f32_16x16x32_bf16(af[i], bfr[j], acc[i][j], 0, 0, 0);
  }
  const int ccol = lane & 15;
  const int crow = (lane >> 4) * 4;
#pragma unroll
  for (int i = 0; i < 4; ++i) {
#pragma unroll
    for (int j = 0; j < 4; ++j) {
      int gn = tn0 + wn + j * 16 + ccol;
      if (gn < Nc) {
        size_t base = (size_t)(tm0 + wm + i * 16 + crow) * Nc + gn;
#pragma unroll
        for (int r = 0; r < 4; ++r) {
          float c = acc[i][j][r];
          size_t idx = base + (size_t)r * Nc;
          if (MODE == 0) {
            C[idx] = c;
          } else if (MODE == 1) {
            float s = c / (1.f + __expf(-c));
            Cb[idx] = f2bf(s);
          } else {
            Cb[idx] = f2bf(c * bf2f(aux[idx]));
          }
        }
      }
    }
  }
}

// ---------------------------------------------------------------------------
__device__ inline float block_reduce_sum_256(float v) {
  __shared__ float red[4];
  int lane = threadIdx.x & 63, wave = threadIdx.x >> 6;
#pragma unroll
  for (int m = 32; m > 0; m >>= 1) v += __shfl_xor(v, m, 64);
  if (lane == 0) red[wave] = v;
  __syncthreads();
  return red[0] + red[1] + red[2] + red[3];
}

// rmsnorm over C=2048 -> bf16 out
__global__ __launch_bounds__(256)
void rmsnorm2048_k(const float* __restrict__ x, const float* __restrict__ w,
                   u16* __restrict__ y) {
  const int C = 2048;
  const int row = blockIdx.x;
  const int t = threadIdx.x;
  const float4* xr = (const float4*)(x + (size_t)row * C);
  float4 v0 = xr[t];
  float4 v1 = xr[t + 256];
  float ss = v0.x * v0.x + v0.y * v0.y + v0.z * v0.z + v0.w * v0.w +
             v1.x * v1.x + v1.y * v1.y + v1.z * v1.z + v1.w * v1.w;
  float tot = block_reduce_sum_256(ss);
  float sc = rsqrtf(tot * (1.0f / C) + 1e-6f);
  const float4* wr = (const float4*)w;
  float4 w0 = wr[t], w1 = wr[t + 256];
  u16* yr = y + (size_t)row * C;
  s16x4 o0, o1;
  o0[0] = (short)f2bf(v0.x * sc * w0.x); o0[1] = (short)f2bf(v0.y * sc * w0.y);
  o0[2] = (short)f2bf(v0.z * sc * w0.z); o0[3] = (short)f2bf(v0.w * sc * w0.w);
  o1[0] = (short)f2bf(v1.x * sc * w1.x); o1[1] = (short)f2bf(v1.y * sc * w1.y);
  o1[2] = (short)f2bf(v1.z * sc * w1.z); o1[3] = (short)f2bf(v1.w * sc * w1.w);
  *(s16x4*)(yr + t * 4) = o0;
  *(s16x4*)(yr + 1024 + t * 4) = o1;
}

// residual = a + b (fp32 store), x2 = bf16(rmsnorm(residual)*w)
__global__ __launch_bounds__(256)
void add_rmsnorm_k(const float* __restrict__ a, const float* __restrict__ b,
                   const float* __restrict__ w, float* __restrict__ resid,
                   u16* __restrict__ y) {
  const int C = 2048;
  const int row = blockIdx.x;
  const int t = threadIdx.x;
  const float4* ar = (const float4*)(a + (size_t)row * C);
  const float4* br = (const float4*)(b + (size_t)row * C);
  float4 v0 = ar[t], v1 = ar[t + 256];
  float4 u0 = br[t], u1 = br[t + 256];
  v0.x += u0.x; v0.y += u0.y; v0.z += u0.z; v0.w += u0.w;
  v1.x += u1.x; v1.y += u1.y; v1.z += u1.z; v1.w += u1.w;
  float4* rr = (float4*)(resid + (size_t)row * C);
  rr[t] = v0; rr[t + 256] = v1;
  float ss = v0.x * v0.x + v0.y * v0.y + v0.z * v0.z + v0.w * v0.w +
             v1.x * v1.x + v1.y * v1.y + v1.z * v1.z + v1.w * v1.w;
  float tot = block_reduce_sum_256(ss);
  float sc = rsqrtf(tot * (1.0f / C) + 1e-6f);
  const float4* wr = (const float4*)w;
  float4 w0 = wr[t], w1 = wr[t + 256];
  u16* yr = y + (size_t)row * C;
  s16x4 o0, o1;
  o0[0] = (short)f2bf(v0.x * sc * w0.x); o0[1] = (short)f2bf(v0.y * sc * w0.y);
  o0[2] = (short)f2bf(v0.z * sc * w0.z); o0[3] = (short)f2bf(v0.w * sc * w0.w);
  o1[0] = (short)f2bf(v1.x * sc * w1.x); o1[1] = (short)f2bf(v1.y * sc * w1.y);
  o1[2] = (short)f2bf(v1.z * sc * w1.z); o1[3] = (short)f2bf(v1.w * sc * w1.w);
  *(s16x4*)(yr + t * 4) = o0;
  *(s16x4*)(yr + 1024 + t * 4) = o1;
}

// causal depthwise conv (K=4) + bias + silu -> bf16 h
__global__ __launch_bounds__(256)
void conv_silu_k(const float* __restrict__ proj, const float* __restrict__ cw,
                 const float* __restrict__ cb, u16* __restrict__ h) {
  const int Di = 4096, LD = 8192;
  int idx = blockIdx.x * 256 + threadIdx.x;
  int d = idx & (Di - 1);
  int l = idx >> 12;
  float4 w = *(const float4*)(cw + (size_t)d * 4);
  float acc = cb[d];
  int ls0 = l - 3;
  if (ls0 >= 0) acc += proj[(size_t)ls0 * LD + d] * w.x;
  if (ls0 + 1 >= 0) acc += proj[(size_t)(ls0 + 1) * LD + d] * w.y;
  if (ls0 + 2 >= 0) acc += proj[(size_t)(ls0 + 2) * LD + d] * w.z;
  acc += proj[(size_t)l * LD + d] * w.w;
  float sig = 1.0f / (1.0f + __expf(-acc));
  h[idx] = f2bf(acc * sig);
}

// three rmsnorms over the 160-wide ssm rows: dt[128]->bf16, B[16], C[16]
__global__ __launch_bounds__(64)
void ssm_norm_k(const float* __restrict__ ssm, const float* __restrict__ dtw,
                const float* __restrict__ bw, const float* __restrict__ cw,
                u16* __restrict__ dtn, float* __restrict__ Bn,
                float* __restrict__ Cn) {
  int l = blockIdx.x;
  int lane = threadIdx.x;
  const float* r = ssm + (size_t)l * 160;
  float d0 = r[lane];
  float d1 = r[lane + 64];
  float bv = (lane < 16) ? r[128 + lane] : 0.f;
  float cv = (lane < 16) ? r[144 + lane] : 0.f;
  float sd = d0 * d0 + d1 * d1;
  float sb = bv * bv;
  float sc = cv * cv;
#pragma unroll
  for (int m = 32; m > 0; m >>= 1) {
    sd += __shfl_xor(sd, m, 64);
    sb += __shfl_xor(sb, m, 64);
    sc += __shfl_xor(sc, m, 64);
  }
  float scd = rsqrtf(sd * (1.f / 128.f) + 1e-6f);
  float scb = rsqrtf(sb * (1.f / 16.f) + 1e-6f);
  float scc = rsqrtf(sc * (1.f / 16.f) + 1e-6f);
  dtn[(size_t)l * 128 + lane] = f2bf(d0 * scd * dtw[lane]);
  dtn[(size_t)l * 128 + lane + 64] = f2bf(d1 * scd * dtw[lane + 64]);
  if (lane < 16) {
    Bn[(size_t)l * 16 + lane] = bv * scb * bw[lane];
    Cn[(size_t)l * 16 + lane] = cv * scc * cw[lane];
  }
}

// delta = softplus(delta_pre + bias[d]) in place (fp32)
__global__ __launch_bounds__(256)
void softplus_bias_k(float* __restrict__ dp, const float* __restrict__ b) {
  const int Di = 4096;
  int i = blockIdx.x * 256 + threadIdx.x;
  int d = i & (Di - 1);
  float x = dp[i] + b[d];
  dp[i] = (x > 20.f) ? x : log1pf(__expf(x));
}

// selective scan: thread = (d,n); wave-reduce over 16 n-lanes; fused gate silu
__global__ __launch_bounds__(256)
void scan_k(const float* __restrict__ delta, const u16* __restrict__ h,
            const float* __restrict__ Bn, const float* __restrict__ Cn,
            const float* __restrict__ Amat, const float* __restrict__ Dw,
            const float* __restrict__ proj, u16* __restrict__ y) {
  const int Di = 4096, L = 1024;
  int t = blockIdx.x * 256 + threadIdx.x;
  int d = t >> 4;
  int n = t & 15;
  float a = Amat[(size_t)d * 16 + n];
  float Dd = Dw[d];
  float s = 0.f;
  __shared__ float Bs[64 * 16];
  __shared__ float Cs[64 * 16];
  for (int lt = 0; lt < L; lt += 64) {
    __syncthreads();
    for (int i = threadIdx.x; i < 1024; i += 256) {
      Bs[i] = Bn[(size_t)lt * 16 + i];
      Cs[i] = Cn[(size_t)lt * 16 + i];
    }
    __syncthreads();
    for (int j = 0; j < 64; ++j) {
      int l = lt + j;
      float del = delta[(size_t)l * Di + d];
      float hv = bf2f(h[(size_t)l * Di + d]);
      float dA = __expf(del * a);
      s = dA * s + del * Bs[j * 16 + n] * hv;
      float p = s * Cs[j * 16 + n];
      p += __shfl_xor(p, 1, 64);
      p += __shfl_xor(p, 2, 64);
      p += __shfl_xor(p, 4, 64);
      p += __shfl_xor(p, 8, 64);
      if (n == 0) {
        float g = proj[(size_t)l * 8192 + 4096 + d];
        float yv = p + hv * Dd;
        y[(size_t)l * Di + d] = f2bf(yv * g / (1.f + __expf(-g)));
      }
    }
  }
}

// out += ff
__global__ __launch_bounds__(256)
void add_k(float* __restrict__ out, const float* __restrict__ ff) {
  int i = blockIdx.x * 256 + threadIdx.x;
  float4 a = ((const float4*)out)[i];
  float4 b = ((const float4*)ff)[i];
  a.x += b.x; a.y += b.y; a.z += b.z; a.w += b.w;
  ((float4*)out)[i] = a;
}

// ---------------------------------------------------------------------------
extern "C" void kernel_launch(void* const* d_in, const int* in_sizes, int n_in,
                              void* d_out, int out_size, void* d_ws, size_t ws_size,
                              hipStream_t stream) {
  const float* hidden      = (const float*)d_in[0];
  const float* in_ln_w     = (const float*)d_in[1];
  const float* pre_ff_ln_w = (const float*)d_in[2];
  const float* in_proj_w   = (const float*)d_in[3];
  const float* conv_w      = (const float*)d_in[4];
  const float* conv_b      = (const float*)d_in[5];
  const float* x_proj_w    = (const float*)d_in[6];
  const float* dt_ln_w     = (const float*)d_in[7];
  const float* b_ln_w      = (const float*)d_in[8];
  const float* c_ln_w      = (const float*)d_in[9];
  const float* dt_proj_w   = (const float*)d_in[10];
  const float* dt_proj_b   = (const float*)d_in[11];
  const float* Amat        = (const float*)d_in[12];
  const float* Dw          = (const float*)d_in[13];
  const float* out_proj_w  = (const float*)d_in[14];
  const float* gate_up_w   = (const float*)d_in[15];
  const float* down_w      = (const float*)d_in[16];
  float* out = (float*)d_out;
  float* ws = (float*)d_ws;

  const int L = 1024, H = 2048, Di = 4096, F = 8192;

  // workspace (float-element offsets), max usage ~106 MB
  u16*   wbuf  = (u16*)ws;                  // up to 16.78M bf16 (weight slab)
  float* proj  = ws + 8388608;              // L x 8192 fp32
  float* dpre  = ws + 16777216;             // L x 4096 fp32 (delta)
  u16*   hbuf  = (u16*)(ws + 20971520);     // L x 4096 bf16
  u16*   xnorm = (u16*)(ws + 23068672);     // L x 2048 bf16
  float* ssm   = ws + 24117248;             // L x 160 fp32
  u16*   dtn   = (u16*)(ws + 24281088);     // L x 128 bf16
  float* Bn    = ws + 24346624;             // L x 16
  float* Cn    = ws + 24363008;             // L x 16
  u16*   ybuf  = (u16*)(ws + 24379392);     // L x 4096 bf16
  float* mix   = ws + 16777216;             // L x 2048 fp32 (reuse dpre, post-scan)
  u16*   x2    = (u16*)(ws + 18874368);     // L x 2048 bf16 (reuse dpre)
  u16*   sg    = (u16*)(ws + 8388608);      // L x 8192 bf16 (reuse proj)
  u16*   x3    = (u16*)(ws + 12582912);     // L x 8192 bf16 (reuse proj)
  float* ff    = ws + 19922944;             // L x 2048 fp32 (reuse dpre/hbuf tail)

  // 1. x_norm = bf16(rmsnorm(hidden))
  rmsnorm2048_k<<<L, 256, 0, stream>>>(hidden, in_ln_w, xnorm);
  // 2. proj = x_norm @ in_proj_w.T  (N=8192, K=2048)
  f32_to_bf16_k<<<16384, 256, 0, stream>>>(in_proj_w, wbuf, 16777216, 16777216);
  gemm_bf16<0><<<dim3(64, 8), 256, 0, stream>>>(xnorm, wbuf, proj, nullptr, nullptr, L, 8192, 2048);
  // 3. h = bf16(silu(conv(proj[:, :Di]) + conv_b))
  conv_silu_k<<<(L * Di) / 256, 256, 0, stream>>>(proj, conv_w, conv_b, hbuf);
  // 4. ssm = h @ x_proj_w.T  (N=160 padded to 256, K=4096)
  f32_to_bf16_k<<<1024, 256, 0, stream>>>(x_proj_w, wbuf, 1048576, 655360);
  gemm_bf16<0><<<dim3(2, 8), 256, 0, stream>>>(hbuf, wbuf, ssm, nullptr, nullptr, L, 160, 4096);
  // 5. split rmsnorms
  ssm_norm_k<<<L, 64, 0, stream>>>(ssm, dt_ln_w, b_ln_w, c_ln_w, dtn, Bn, Cn);
  // 6. delta_pre = dtn @ dt_proj_w.T  (N=4096, K=128)
  f32_to_bf16_k<<<512, 256, 0, stream>>>(dt_proj_w, wbuf, 524288, 524288);
  gemm_bf16<0><<<dim3(32, 8), 256, 0, stream>>>(dtn, wbuf, dpre, nullptr, nullptr, L, 4096, 128);
  // 7. delta = softplus(delta_pre + dt_proj_b)
  softplus_bias_k<<<(L * Di) / 256, 256, 0, stream>>>(dpre, dt_proj_b);
  // 8. selective scan + gate silu -> ybuf (bf16)
  scan_k<<<(Di * 16) / 256, 256, 0, stream>>>(dpre, hbuf, Bn, Cn, Amat, Dw, proj, ybuf);
  // 9. mix = y @ out_proj_w.T  (N=2048, K=4096)
  f32_to_bf16_k<<<8192, 256, 0, stream>>>(out_proj_w, wbuf, 8388608, 8388608);
  gemm_bf16<0><<<dim3(16, 8), 256, 0, stream>>>(ybuf, wbuf, mix, nullptr, nullptr, L, 2048, 4096);
  // 10. residual(out) = hidden + mix ; x2 = bf16(rmsnorm(residual))
  add_rmsnorm_k<<<L, 256, 0, stream>>>(hidden, mix, pre_ff_ln_w, out, x2);
  // 11a. sg = bf16(silu(x2 @ gate_w.T))  (N=8192, K=2048)
  f32_to_bf16_k<<<16384, 256, 0, stream>>>(gate_up_w, wbuf, 16777216, 16777216);
  gemm_bf16<1><<<dim3(64, 8), 256, 0, stream>>>(x2, wbuf, nullptr, sg, nullptr, L, 8192, 2048);
  // 11b. x3 = bf16((x2 @ up_w.T) * sg)
  f32_to_bf16_k<<<16384, 256, 0, stream>>>(gate_up_w + 16777216, wbuf, 16777216, 16777216);
  gemm_bf16<2><<<dim3(64, 8), 256, 0, stream>>>(x2, wbuf, nullptr, x3, sg, L, 8192, 2048);
  // 13. ff = x3 @ down_w.T  (N=2048, K=8192)
  f32_to_bf16_k<<<16384, 256, 0, stream>>>(down_w, wbuf, 16777216, 16777216);
  gemm_bf16<0><<<dim3(16, 8), 256, 0, stream>>>(x3, wbuf, ff, nullptr, nullptr, L, 2048, 8192);
  // 14. out += ff
  add_k<<<(L * H / 4) / 256, 256, 0, stream>>>(out, ff);
}

// Round 3
// 1367.496 us; speedup vs baseline: 2.3300x; 1.2104x over previous
//
#include <hip/hip_runtime.h>
#include <math.h>

typedef unsigned short u16;
typedef __bf16 bf16x8 __attribute__((ext_vector_type(8)));
typedef short s16x8 __attribute__((ext_vector_type(8)));
typedef short s16x4 __attribute__((ext_vector_type(4)));
typedef float f32x4 __attribute__((ext_vector_type(4)));

__device__ __forceinline__ u16 f2bf(float f) {
  union { float f; unsigned u; } v; v.f = f;
  unsigned u = v.u;
  unsigned r = u + 0x7fffu + ((u >> 16) & 1u);
  return (u16)(r >> 16);
}
__device__ __forceinline__ float bf2f(u16 h) {
  union { unsigned u; float f; } v; v.u = ((unsigned)h) << 16;
  return v.f;
}
__device__ __forceinline__ float softplus_f(float x) {
  return (x > 20.f) ? x : log1pf(__expf(x));
}

__device__ __forceinline__ void gld_lds16(const u16* g, u16* l) {
  __builtin_amdgcn_global_load_lds(
      (const __attribute__((address_space(1))) unsigned int*)g,
      (__attribute__((address_space(3))) unsigned int*)l, 16, 0, 0);
}

// ---------------------------------------------------------------------------
// fp32 -> bf16 weight conversion, zero-pads [n_valid, n)
__global__ __launch_bounds__(256)
void f32_to_bf16_k(const float* __restrict__ src, u16* __restrict__ dst,
                   int n, int n_valid) {
  int i = (blockIdx.x * 256 + threadIdx.x) * 4;
  if (i >= n) return;
  s16x4 o;
  if (i + 3 < n_valid) {
    float4 v = *(const float4*)(src + i);
    o[0] = (short)f2bf(v.x); o[1] = (short)f2bf(v.y);
    o[2] = (short)f2bf(v.z); o[3] = (short)f2bf(v.w);
  } else {
    o[0] = 0; o[1] = 0; o[2] = 0; o[3] = 0;
  }
  *(s16x4*)(dst + i) = o;
}

// ---------------------------------------------------------------------------
// GEMM (m97 structure): C[M,N] = A[M,K](bf16) @ B[N,K](bf16)^T
// MODE 0: C fp32.  MODE 1: Cb = bf16(silu(c)).  MODE 2: Cb = bf16(c*aux).
template <int MODE>
__global__ __launch_bounds__(256)
void gemm_bf16(const u16* __restrict__ A, const u16* __restrict__ B,
               float* __restrict__ C, u16* __restrict__ Cb,
               const u16* __restrict__ aux, int M, int Nc, int K) {
  __shared__ __align__(16) u16 As[128 * 32];
  __shared__ __align__(16) u16 Bs[128 * 32];
  const int tid = threadIdx.x;
  const int tm0 = blockIdx.y * 128;
  const int tn0 = blockIdx.x * 128;
  const int wave = tid >> 6;
  const int lane = tid & 63;
  const int wm = (wave >> 1) * 64;
  const int wn = (wave & 1) * 64;
  const int frow = lane & 15;
  const int fk = (lane >> 4) * 8;

  const int r0 = tid >> 2;
  const int c0 = (tid & 3) << 3;
  const u16* gA = A + (size_t)(tm0 + r0) * K + c0;
  const u16* gB = B + (size_t)(tn0 + r0) * K + c0;
  const size_t half = (size_t)64 * K;
  u16* lA = &As[tid * 8];
  u16* lB = &Bs[tid * 8];

  f32x4 acc[4][4];
  f32x4 zero = {0.f, 0.f, 0.f, 0.f};
#pragma unroll
  for (int i = 0; i < 4; ++i)
#pragma unroll
    for (int j = 0; j < 4; ++j) acc[i][j] = zero;

  for (int kt = 0; kt < K; kt += 32) {
    __syncthreads();
    gld_lds16(gA, lA);
    gld_lds16(gA + half, lA + 2048);
    gld_lds16(gB, lB);
    gld_lds16(gB + half, lB + 2048);
    gA += 32; gB += 32;
    __syncthreads();
    bf16x8 af[4], bfr[4];
#pragma unroll
    for (int i = 0; i < 4; ++i) {
      s16x8 raw = *(const s16x8*)&As[(wm + i * 16 + frow) * 32 + fk];
      af[i] = __builtin_bit_cast(bf16x8, raw);
    }
#pragma unroll
    for (int j = 0; j < 4; ++j) {
      s16x8 raw = *(const s16x8*)&Bs[(wn + j * 16 + frow) * 32 + fk];
      bfr[j] = __builtin_bit_cast(bf16x8, raw);
    }
#pragma unroll
    for (int i = 0; i < 4; ++i)
#pragma unroll
      for (int j = 0; j < 4; ++j)
        acc[i][j] = __builtin_amdgcn_mfma_f32_16x16x32_bf16(af[i], bfr[j], acc[i][j], 0, 0, 0);
  }
  const int ccol = lane & 15;
  const int crow = (lane >> 4) * 4;
#pragma unroll
  for (int i = 0; i < 4; ++i) {
#pragma unroll
    for (int j = 0; j < 4; ++j) {
      int gn = tn0 + wn + j * 16 + ccol;
      if (gn < Nc) {
        size_t base = (size_t)(tm0 + wm + i * 16 + crow) * Nc + gn;
#pragma unroll
        for (int r = 0; r < 4; ++r) {
          float c = acc[i][j][r];
          size_t idx = base + (size_t)r * Nc;
          if (MODE == 0) {
            C[idx] = c;
          } else if (MODE == 1) {
            float s = c / (1.f + __expf(-c));
            Cb[idx] = f2bf(s);
          } else {
            Cb[idx] = f2bf(c * bf2f(aux[idx]));
          }
        }
      }
    }
  }
}

// ---------------------------------------------------------------------------
__device__ inline float block_reduce_sum_256(float v) {
  __shared__ float red[4];
  int lane = threadIdx.x & 63, wave = threadIdx.x >> 6;
#pragma unroll
  for (int m = 32; m > 0; m >>= 1) v += __shfl_xor(v, m, 64);
  if (lane == 0) red[wave] = v;
  __syncthreads();
  return red[0] + red[1] + red[2] + red[3];
}

// rmsnorm over C=2048 -> bf16 out
__global__ __launch_bounds__(256)
void rmsnorm2048_k(const float* __restrict__ x, const float* __restrict__ w,
                   u16* __restrict__ y) {
  const int C = 2048;
  const int row = blockIdx.x;
  const int t = threadIdx.x;
  const float4* xr = (const float4*)(x + (size_t)row * C);
  float4 v0 = xr[t];
  float4 v1 = xr[t + 256];
  float ss = v0.x * v0.x + v0.y * v0.y + v0.z * v0.z + v0.w * v0.w +
             v1.x * v1.x + v1.y * v1.y + v1.z * v1.z + v1.w * v1.w;
  float tot = block_reduce_sum_256(ss);
  float sc = rsqrtf(tot * (1.0f / C) + 1e-6f);
  const float4* wr = (const float4*)w;
  float4 w0 = wr[t], w1 = wr[t + 256];
  u16* yr = y + (size_t)row * C;
  s16x4 o0, o1;
  o0[0] = (short)f2bf(v0.x * sc * w0.x); o0[1] = (short)f2bf(v0.y * sc * w0.y);
  o0[2] = (short)f2bf(v0.z * sc * w0.z); o0[3] = (short)f2bf(v0.w * sc * w0.w);
  o1[0] = (short)f2bf(v1.x * sc * w1.x); o1[1] = (short)f2bf(v1.y * sc * w1.y);
  o1[2] = (short)f2bf(v1.z * sc * w1.z); o1[3] = (short)f2bf(v1.w * sc * w1.w);
  *(s16x4*)(yr + t * 4) = o0;
  *(s16x4*)(yr + 1024 + t * 4) = o1;
}

// residual = a + b (fp32 store), x2 = bf16(rmsnorm(residual)*w)
__global__ __launch_bounds__(256)
void add_rmsnorm_k(const float* __restrict__ a, const float* __restrict__ b,
                   const float* __restrict__ w, float* __restrict__ resid,
                   u16* __restrict__ y) {
  const int C = 2048;
  const int row = blockIdx.x;
  const int t = threadIdx.x;
  const float4* ar = (const float4*)(a + (size_t)row * C);
  const float4* br = (const float4*)(b + (size_t)row * C);
  float4 v0 = ar[t], v1 = ar[t + 256];
  float4 u0 = br[t], u1 = br[t + 256];
  v0.x += u0.x; v0.y += u0.y; v0.z += u0.z; v0.w += u0.w;
  v1.x += u1.x; v1.y += u1.y; v1.z += u1.z; v1.w += u1.w;
  float4* rr = (float4*)(resid + (size_t)row * C);
  rr[t] = v0; rr[t + 256] = v1;
  float ss = v0.x * v0.x + v0.y * v0.y + v0.z * v0.z + v0.w * v0.w +
             v1.x * v1.x + v1.y * v1.y + v1.z * v1.z + v1.w * v1.w;
  float tot = block_reduce_sum_256(ss);
  float sc = rsqrtf(tot * (1.0f / C) + 1e-6f);
  const float4* wr = (const float4*)w;
  float4 w0 = wr[t], w1 = wr[t + 256];
  u16* yr = y + (size_t)row * C;
  s16x4 o0, o1;
  o0[0] = (short)f2bf(v0.x * sc * w0.x); o0[1] = (short)f2bf(v0.y * sc * w0.y);
  o0[2] = (short)f2bf(v0.z * sc * w0.z); o0[3] = (short)f2bf(v0.w * sc * w0.w);
  o1[0] = (short)f2bf(v1.x * sc * w1.x); o1[1] = (short)f2bf(v1.y * sc * w1.y);
  o1[2] = (short)f2bf(v1.z * sc * w1.z); o1[3] = (short)f2bf(v1.w * sc * w1.w);
  *(s16x4*)(yr + t * 4) = o0;
  *(s16x4*)(yr + 1024 + t * 4) = o1;
}

// causal depthwise conv (K=4) + bias + silu -> bf16 h
__global__ __launch_bounds__(256)
void conv_silu_k(const float* __restrict__ proj, const float* __restrict__ cw,
                 const float* __restrict__ cb, u16* __restrict__ h) {
  const int Di = 4096, LD = 8192;
  int idx = blockIdx.x * 256 + threadIdx.x;
  int d = idx & (Di - 1);
  int l = idx >> 12;
  float4 w = *(const float4*)(cw + (size_t)d * 4);
  float acc = cb[d];
  int ls0 = l - 3;
  if (ls0 >= 0) acc += proj[(size_t)ls0 * LD + d] * w.x;
  if (ls0 + 1 >= 0) acc += proj[(size_t)(ls0 + 1) * LD + d] * w.y;
  if (ls0 + 2 >= 0) acc += proj[(size_t)(ls0 + 2) * LD + d] * w.z;
  acc += proj[(size_t)l * LD + d] * w.w;
  float sig = 1.0f / (1.0f + __expf(-acc));
  h[idx] = f2bf(acc * sig);
}

// three rmsnorms over the 160-wide ssm rows: dt[128]->bf16, B[16], C[16]
__global__ __launch_bounds__(64)
void ssm_norm_k(const float* __restrict__ ssm, const float* __restrict__ dtw,
                const float* __restrict__ bw, const float* __restrict__ cw,
                u16* __restrict__ dtn, float* __restrict__ Bn,
                float* __restrict__ Cn) {
  int l = blockIdx.x;
  int lane = threadIdx.x;
  const float* r = ssm + (size_t)l * 160;
  float d0 = r[lane];
  float d1 = r[lane + 64];
  float bv = (lane < 16) ? r[128 + lane] : 0.f;
  float cv = (lane < 16) ? r[144 + lane] : 0.f;
  float sd = d0 * d0 + d1 * d1;
  float sb = bv * bv;
  float sc = cv * cv;
#pragma unroll
  for (int m = 32; m > 0; m >>= 1) {
    sd += __shfl_xor(sd, m, 64);
    sb += __shfl_xor(sb, m, 64);
    sc += __shfl_xor(sc, m, 64);
  }
  float scd = rsqrtf(sd * (1.f / 128.f) + 1e-6f);
  float scb = rsqrtf(sb * (1.f / 16.f) + 1e-6f);
  float scc = rsqrtf(sc * (1.f / 16.f) + 1e-6f);
  dtn[(size_t)l * 128 + lane] = f2bf(d0 * scd * dtw[lane]);
  dtn[(size_t)l * 128 + lane + 64] = f2bf(d1 * scd * dtw[lane + 64]);
  if (lane < 16) {
    Bn[(size_t)l * 16 + lane] = bv * scb * bw[lane];
    Cn[(size_t)l * 16 + lane] = cv * scc * cw[lane];
  }
}

// ---------------------------------------------------------------------------
// Chunked parallel scan over L=1024 in 16 chunks of 64.
// pair = d*16+n (65536 pairs). Phase 1: local scan -> (prod dA, s_end).
#define NCH 16
#define CHL 64

__global__ __launch_bounds__(256)
void scan_p1(const float* __restrict__ dpre, const float* __restrict__ dtb,
             const u16* __restrict__ h, const float* __restrict__ Bn,
             const float* __restrict__ Amat,
             float* __restrict__ carryA, float* __restrict__ carryS) {
  const int Di = 4096;
  int tg = blockIdx.x * 256 + threadIdx.x;
  int chunk = tg >> 16;
  int pair = tg & 65535;
  int d = pair >> 4, n = pair & 15;
  __shared__ float Bs[CHL * 16];
  for (int i = threadIdx.x; i < CHL * 16; i += 256)
    Bs[i] = Bn[(size_t)chunk * CHL * 16 + i];
  __syncthreads();
  float a = Amat[(size_t)d * 16 + n];
  float bias = dtb[d];
  float s = 0.f, ap = 1.f;
  int l0 = chunk * CHL;
#pragma unroll 4
  for (int j = 0; j < CHL; ++j) {
    int l = l0 + j;
    float del = softplus_f(dpre[(size_t)l * Di + d] + bias);
    float hv = bf2f(h[(size_t)l * Di + d]);
    float dA = __expf(del * a);
    s = dA * s + del * Bs[j * 16 + n] * hv;
    ap *= dA;
  }
  carryA[(size_t)chunk * 65536 + pair] = ap;
  carryS[(size_t)chunk * 65536 + pair] = s;
}

// Phase 2: per pair, sequential combine over chunks; carryS <- carry-IN.
__global__ __launch_bounds__(256)
void scan_p2(const float* __restrict__ carryA, float* __restrict__ carryS) {
  int p = blockIdx.x * 256 + threadIdx.x;
  float av[NCH], sv[NCH];
#pragma unroll
  for (int c = 0; c < NCH; ++c) {
    av[c] = carryA[(size_t)c * 65536 + p];
    sv[c] = carryS[(size_t)c * 65536 + p];
  }
  float cin = 0.f;
#pragma unroll
  for (int c = 0; c < NCH; ++c) {
    float nx = av[c] * cin + sv[c];
    carryS[(size_t)c * 65536 + p] = cin;
    cin = nx;
  }
}

// Phase 3: local scan with carry-in; fused y = (s.C + h*D)*silu(gate) -> bf16
__global__ __launch_bounds__(256)
void scan_p3(const float* __restrict__ dpre, const float* __restrict__ dtb,
             const u16* __restrict__ h, const float* __restrict__ Bn,
             const float* __restrict__ Cn, const float* __restrict__ Amat,
             const float* __restrict__ Dw, const float* __restrict__ proj,
             const float* __restrict__ carryS, u16* __restrict__ y) {
  const int Di = 4096;
  int tg = blockIdx.x * 256 + threadIdx.x;
  int chunk = tg >> 16;
  int pair = tg & 65535;
  int d = pair >> 4, n = pair & 15;
  __shared__ float Bs[CHL * 16];
  __shared__ float Cs[CHL * 16];
  for (int i = threadIdx.x; i < CHL * 16; i += 256) {
    Bs[i] = Bn[(size_t)chunk * CHL * 16 + i];
    Cs[i] = Cn[(size_t)chunk * CHL * 16 + i];
  }
  __syncthreads();
  float a = Amat[(size_t)d * 16 + n];
  float bias = dtb[d];
  float Dd = Dw[d];
  float s = carryS[(size_t)chunk * 65536 + pair];
  int l0 = chunk * CHL;
#pragma unroll 4
  for (int j = 0; j < CHL; ++j) {
    int l = l0 + j;
    float del = softplus_f(dpre[(size_t)l * Di + d] + bias);
    float hv = bf2f(h[(size_t)l * Di + d]);
    float dA = __expf(del * a);
    s = dA * s + del * Bs[j * 16 + n] * hv;
    float p = s * Cs[j * 16 + n];
    p += __shfl_xor(p, 1, 64);
    p += __shfl_xor(p, 2, 64);
    p += __shfl_xor(p, 4, 64);
    p += __shfl_xor(p, 8, 64);
    if (n == 0) {
      float g = proj[(size_t)l * 8192 + 4096 + d];
      float yv = p + hv * Dd;
      y[(size_t)l * Di + d] = f2bf(yv * g / (1.f + __expf(-g)));
    }
  }
}

// out += ff
__global__ __launch_bounds__(256)
void add_k(float* __restrict__ out, const float* __restrict__ ff) {
  int i = blockIdx.x * 256 + threadIdx.x;
  float4 a = ((const float4*)out)[i];
  float4 b = ((const float4*)ff)[i];
  a.x += b.x; a.y += b.y; a.z += b.z; a.w += b.w;
  ((float4*)out)[i] = a;
}

// ---------------------------------------------------------------------------
extern "C" void kernel_launch(void* const* d_in, const int* in_sizes, int n_in,
                              void* d_out, int out_size, void* d_ws, size_t ws_size,
                              hipStream_t stream) {
  const float* hidden      = (const float*)d_in[0];
  const float* in_ln_w     = (const float*)d_in[1];
  const float* pre_ff_ln_w = (const float*)d_in[2];
  const float* in_proj_w   = (const float*)d_in[3];
  const float* conv_w      = (const float*)d_in[4];
  const float* conv_b      = (const float*)d_in[5];
  const float* x_proj_w    = (const float*)d_in[6];
  const float* dt_ln_w     = (const float*)d_in[7];
  const float* b_ln_w      = (const float*)d_in[8];
  const float* c_ln_w      = (const float*)d_in[9];
  const float* dt_proj_w   = (const float*)d_in[10];
  const float* dt_proj_b   = (const float*)d_in[11];
  const float* Amat        = (const float*)d_in[12];
  const float* Dw          = (const float*)d_in[13];
  const float* out_proj_w  = (const float*)d_in[14];
  const float* gate_up_w   = (const float*)d_in[15];
  const float* down_w      = (const float*)d_in[16];
  float* out = (float*)d_out;
  float* ws = (float*)d_ws;

  const int L = 1024, H = 2048, Di = 4096, F = 8192;

  // workspace (float-element offsets), peak ~110 MB
  u16*   wbuf   = (u16*)ws;                  // weight slab (bf16)
  float* proj   = ws + 8388608;              // L x 8192 fp32
  float* dpre   = ws + 16777216;             // L x 4096 fp32 (raw dt GEMM out)
  u16*   hbuf   = (u16*)(ws + 20971520);     // L x 4096 bf16
  u16*   xnorm  = (u16*)(ws + 23068672);     // L x 2048 bf16 (dead after step 2)
  float* carryA = ws + 23068672;             // 16 x 65536 (reuses xnorm space)
  float* ssm    = ws + 24117248;             // L x 160 fp32
  u16*   dtn    = (u16*)(ws + 24281088);     // L x 128 bf16
  float* Bn     = ws + 24346624;             // L x 16
  float* Cn     = ws + 24363008;             // L x 16
  u16*   ybuf   = (u16*)(ws + 24379392);     // L x 4096 bf16
  float* carryS = ws + 26476544;             // 16 x 65536
  float* mix    = ws + 16777216;             // L x 2048 fp32 (reuse dpre, post-scan)
  u16*   x2     = (u16*)(ws + 18874368);     // L x 2048 bf16 (reuse dpre tail)
  u16*   sg     = (u16*)(ws + 8388608);      // L x 8192 bf16 (reuse proj)
  u16*   x3     = (u16*)(ws + 12582912);     // L x 8192 bf16 (reuse proj)
  float* ff     = ws + 19922944;             // L x 2048 fp32

  // 1. x_norm = bf16(rmsnorm(hidden))
  rmsnorm2048_k<<<L, 256, 0, stream>>>(hidden, in_ln_w, xnorm);
  // 2. proj = x_norm @ in_proj_w.T  (N=8192, K=2048)
  f32_to_bf16_k<<<16384, 256, 0, stream>>>(in_proj_w, wbuf, 16777216, 16777216);
  gemm_bf16<0><<<dim3(64, 8), 256, 0, stream>>>(xnorm, wbuf, proj, nullptr, nullptr, L, 8192, 2048);
  // 3. h = bf16(silu(conv(proj[:, :Di]) + conv_b))
  conv_silu_k<<<(L * Di) / 256, 256, 0, stream>>>(proj, conv_w, conv_b, hbuf);
  // 4. ssm = h @ x_proj_w.T  (N=160 padded to 256, K=4096)
  f32_to_bf16_k<<<1024, 256, 0, stream>>>(x_proj_w, wbuf, 1048576, 655360);
  gemm_bf16<0><<<dim3(2, 8), 256, 0, stream>>>(hbuf, wbuf, ssm, nullptr, nullptr, L, 160, 4096);
  // 5. split rmsnorms
  ssm_norm_k<<<L, 64, 0, stream>>>(ssm, dt_ln_w, b_ln_w, c_ln_w, dtn, Bn, Cn);
  // 6. delta_pre = dtn @ dt_proj_w.T  (N=4096, K=128)
  f32_to_bf16_k<<<512, 256, 0, stream>>>(dt_proj_w, wbuf, 524288, 524288);
  gemm_bf16<0><<<dim3(32, 8), 256, 0, stream>>>(dtn, wbuf, dpre, nullptr, nullptr, L, 4096, 128);
  // 7-8. chunked scan (softplus fused) + gate silu -> ybuf (bf16)
  scan_p1<<<4096, 256, 0, stream>>>(dpre, dt_proj_b, hbuf, Bn, Amat, carryA, carryS);
  scan_p2<<<256, 256, 0, stream>>>(carryA, carryS);
  scan_p3<<<4096, 256, 0, stream>>>(dpre, dt_proj_b, hbuf, Bn, Cn, Amat, Dw, proj, carryS, ybuf);
  // 9. mix = y @ out_proj_w.T  (N=2048, K=4096)
  f32_to_bf16_k<<<8192, 256, 0, stream>>>(out_proj_w, wbuf, 8388608, 8388608);
  gemm_bf16<0><<<dim3(16, 8), 256, 0, stream>>>(ybuf, wbuf, mix, nullptr, nullptr, L, 2048, 4096);
  // 10. residual(out) = hidden + mix ; x2 = bf16(rmsnorm(residual))
  add_rmsnorm_k<<<L, 256, 0, stream>>>(hidden, mix, pre_ff_ln_w, out, x2);
  // 11a. sg = bf16(silu(x2 @ gate_w.T))  (N=8192, K=2048)
  f32_to_bf16_k<<<16384, 256, 0, stream>>>(gate_up_w, wbuf, 16777216, 16777216);
  gemm_bf16<1><<<dim3(64, 8), 256, 0, stream>>>(x2, wbuf, nullptr, sg, nullptr, L, 8192, 2048);
  // 11b. x3 = bf16((x2 @ up_w.T) * sg)
  f32_to_bf16_k<<<16384, 256, 0, stream>>>(gate_up_w + 16777216, wbuf, 16777216, 16777216);
  gemm_bf16<2><<<dim3(64, 8), 256, 0, stream>>>(x2, wbuf, nullptr, x3, sg, L, 8192, 2048);
  // 13. ff = x3 @ down_w.T  (N=2048, K=8192)
  f32_to_bf16_k<<<16384, 256, 0, stream>>>(down_w, wbuf, 16777216, 16777216);
  gemm_bf16<0><<<dim3(16, 8), 256, 0, stream>>>(x3, wbuf, ff, nullptr, nullptr, L, 2048, 8192);
  // 14. out += ff
  add_k<<<(L * H / 4) / 256, 256, 0, stream>>>(out, ff);
}

// Round 4
// 935.855 us; speedup vs baseline: 3.4047x; 1.4612x over previous
//
#include <hip/hip_runtime.h>
#include <math.h>

typedef unsigned short u16;
typedef __bf16 bf16x8 __attribute__((ext_vector_type(8)));
typedef short s16x8 __attribute__((ext_vector_type(8)));
typedef short s16x4 __attribute__((ext_vector_type(4)));
typedef float f32x4 __attribute__((ext_vector_type(4)));

__device__ __forceinline__ u16 f2bf(float f) {
  union { float f; unsigned u; } v; v.f = f;
  unsigned u = v.u;
  unsigned r = u + 0x7fffu + ((u >> 16) & 1u);
  return (u16)(r >> 16);
}
__device__ __forceinline__ float bf2f(u16 h) {
  union { unsigned u; float f; } v; v.u = ((unsigned)h) << 16;
  return v.f;
}
__device__ __forceinline__ float fast_softplus(float x) {
  return (x > 20.f) ? x : __logf(1.f + __expf(x));
}
__device__ __forceinline__ float fast_sig(float x) {
  return __builtin_amdgcn_rcpf(1.f + __expf(-x));
}

__device__ __forceinline__ void gld_lds16(const u16* g, u16* l) {
  __builtin_amdgcn_global_load_lds(
      (const __attribute__((address_space(1))) unsigned int*)g,
      (__attribute__((address_space(3))) unsigned int*)l, 16, 0, 0);
}

// ---------------------------------------------------------------------------
// fp32 -> bf16 weight conversion, zero-pads [n_valid, n)
__global__ __launch_bounds__(256)
void f32_to_bf16_k(const float* __restrict__ src, u16* __restrict__ dst,
                   int n, int n_valid) {
  int i = (blockIdx.x * 256 + threadIdx.x) * 4;
  if (i >= n) return;
  s16x4 o;
  if (i + 3 < n_valid) {
    float4 v = *(const float4*)(src + i);
    o[0] = (short)f2bf(v.x); o[1] = (short)f2bf(v.y);
    o[2] = (short)f2bf(v.z); o[3] = (short)f2bf(v.w);
  } else {
    o[0] = 0; o[1] = 0; o[2] = 0; o[3] = 0;
  }
  *(s16x4*)(dst + i) = o;
}

// ---------------------------------------------------------------------------
// GEMM (m97 structure): C[M,N] = A[M,K](bf16) @ B[N,K](bf16)^T
// MODE 0: C fp32.  MODE 1: Cb = bf16(silu(c)).  MODE 2: Cb = bf16(c*aux).
template <int MODE>
__global__ __launch_bounds__(256)
void gemm_bf16(const u16* __restrict__ A, const u16* __restrict__ B,
               float* __restrict__ C, u16* __restrict__ Cb,
               const u16* __restrict__ aux, int M, int Nc, int K) {
  __shared__ __align__(16) u16 As[128 * 32];
  __shared__ __align__(16) u16 Bs[128 * 32];
  const int tid = threadIdx.x;
  const int tm0 = blockIdx.y * 128;
  const int tn0 = blockIdx.x * 128;
  const int wave = tid >> 6;
  const int lane = tid & 63;
  const int wm = (wave >> 1) * 64;
  const int wn = (wave & 1) * 64;
  const int frow = lane & 15;
  const int fk = (lane >> 4) * 8;

  const int r0 = tid >> 2;
  const int c0 = (tid & 3) << 3;
  const u16* gA = A + (size_t)(tm0 + r0) * K + c0;
  const u16* gB = B + (size_t)(tn0 + r0) * K + c0;
  const size_t half = (size_t)64 * K;
  u16* lA = &As[tid * 8];
  u16* lB = &Bs[tid * 8];

  f32x4 acc[4][4];
  f32x4 zero = {0.f, 0.f, 0.f, 0.f};
#pragma unroll
  for (int i = 0; i < 4; ++i)
#pragma unroll
    for (int j = 0; j < 4; ++j) acc[i][j] = zero;

  for (int kt = 0; kt < K; kt += 32) {
    __syncthreads();
    gld_lds16(gA, lA);
    gld_lds16(gA + half, lA + 2048);
    gld_lds16(gB, lB);
    gld_lds16(gB + half, lB + 2048);
    gA += 32; gB += 32;
    __syncthreads();
    bf16x8 af[4], bfr[4];
#pragma unroll
    for (int i = 0; i < 4; ++i) {
      s16x8 raw = *(const s16x8*)&As[(wm + i * 16 + frow) * 32 + fk];
      af[i] = __builtin_bit_cast(bf16x8, raw);
    }
#pragma unroll
    for (int j = 0; j < 4; ++j) {
      s16x8 raw = *(const s16x8*)&Bs[(wn + j * 16 + frow) * 32 + fk];
      bfr[j] = __builtin_bit_cast(bf16x8, raw);
    }
#pragma unroll
    for (int i = 0; i < 4; ++i)
#pragma unroll
      for (int j = 0; j < 4; ++j)
        acc[i][j] = __builtin_amdgcn_mfma_f32_16x16x32_bf16(af[i], bfr[j], acc[i][j], 0, 0, 0);
  }
  const int ccol = lane & 15;
  const int crow = (lane >> 4) * 4;
#pragma unroll
  for (int i = 0; i < 4; ++i) {
#pragma unroll
    for (int j = 0; j < 4; ++j) {
      int gn = tn0 + wn + j * 16 + ccol;
      if (gn < Nc) {
        size_t base = (size_t)(tm0 + wm + i * 16 + crow) * Nc + gn;
#pragma unroll
        for (int r = 0; r < 4; ++r) {
          float c = acc[i][j][r];
          size_t idx = base + (size_t)r * Nc;
          if (MODE == 0) {
            C[idx] = c;
          } else if (MODE == 1) {
            Cb[idx] = f2bf(c * fast_sig(c));
          } else {
            Cb[idx] = f2bf(c * bf2f(aux[idx]));
          }
        }
      }
    }
  }
}

// ---------------------------------------------------------------------------
__device__ inline float block_reduce_sum_256(float v) {
  __shared__ float red[4];
  int lane = threadIdx.x & 63, wave = threadIdx.x >> 6;
#pragma unroll
  for (int m = 32; m > 0; m >>= 1) v += __shfl_xor(v, m, 64);
  if (lane == 0) red[wave] = v;
  __syncthreads();
  return red[0] + red[1] + red[2] + red[3];
}

// rmsnorm over C=2048 -> bf16 out
__global__ __launch_bounds__(256)
void rmsnorm2048_k(const float* __restrict__ x, const float* __restrict__ w,
                   u16* __restrict__ y) {
  const int C = 2048;
  const int row = blockIdx.x;
  const int t = threadIdx.x;
  const float4* xr = (const float4*)(x + (size_t)row * C);
  float4 v0 = xr[t];
  float4 v1 = xr[t + 256];
  float ss = v0.x * v0.x + v0.y * v0.y + v0.z * v0.z + v0.w * v0.w +
             v1.x * v1.x + v1.y * v1.y + v1.z * v1.z + v1.w * v1.w;
  float tot = block_reduce_sum_256(ss);
  float sc = rsqrtf(tot * (1.0f / C) + 1e-6f);
  const float4* wr = (const float4*)w;
  float4 w0 = wr[t], w1 = wr[t + 256];
  u16* yr = y + (size_t)row * C;
  s16x4 o0, o1;
  o0[0] = (short)f2bf(v0.x * sc * w0.x); o0[1] = (short)f2bf(v0.y * sc * w0.y);
  o0[2] = (short)f2bf(v0.z * sc * w0.z); o0[3] = (short)f2bf(v0.w * sc * w0.w);
  o1[0] = (short)f2bf(v1.x * sc * w1.x); o1[1] = (short)f2bf(v1.y * sc * w1.y);
  o1[2] = (short)f2bf(v1.z * sc * w1.z); o1[3] = (short)f2bf(v1.w * sc * w1.w);
  *(s16x4*)(yr + t * 4) = o0;
  *(s16x4*)(yr + 1024 + t * 4) = o1;
}

// residual = a + b (fp32 store), x2 = bf16(rmsnorm(residual)*w)
__global__ __launch_bounds__(256)
void add_rmsnorm_k(const float* __restrict__ a, const float* __restrict__ b,
                   const float* __restrict__ w, float* __restrict__ resid,
                   u16* __restrict__ y) {
  const int C = 2048;
  const int row = blockIdx.x;
  const int t = threadIdx.x;
  const float4* ar = (const float4*)(a + (size_t)row * C);
  const float4* br = (const float4*)(b + (size_t)row * C);
  float4 v0 = ar[t], v1 = ar[t + 256];
  float4 u0 = br[t], u1 = br[t + 256];
  v0.x += u0.x; v0.y += u0.y; v0.z += u0.z; v0.w += u0.w;
  v1.x += u1.x; v1.y += u1.y; v1.z += u1.z; v1.w += u1.w;
  float4* rr = (float4*)(resid + (size_t)row * C);
  rr[t] = v0; rr[t + 256] = v1;
  float ss = v0.x * v0.x + v0.y * v0.y + v0.z * v0.z + v0.w * v0.w +
             v1.x * v1.x + v1.y * v1.y + v1.z * v1.z + v1.w * v1.w;
  float tot = block_reduce_sum_256(ss);
  float sc = rsqrtf(tot * (1.0f / C) + 1e-6f);
  const float4* wr = (const float4*)w;
  float4 w0 = wr[t], w1 = wr[t + 256];
  u16* yr = y + (size_t)row * C;
  s16x4 o0, o1;
  o0[0] = (short)f2bf(v0.x * sc * w0.x); o0[1] = (short)f2bf(v0.y * sc * w0.y);
  o0[2] = (short)f2bf(v0.z * sc * w0.z); o0[3] = (short)f2bf(v0.w * sc * w0.w);
  o1[0] = (short)f2bf(v1.x * sc * w1.x); o1[1] = (short)f2bf(v1.y * sc * w1.y);
  o1[2] = (short)f2bf(v1.z * sc * w1.z); o1[3] = (short)f2bf(v1.w * sc * w1.w);
  *(s16x4*)(yr + t * 4) = o0;
  *(s16x4*)(yr + 1024 + t * 4) = o1;
}

// causal depthwise conv (K=4) + bias + silu -> bf16 h
__global__ __launch_bounds__(256)
void conv_silu_k(const float* __restrict__ proj, const float* __restrict__ cw,
                 const float* __restrict__ cb, u16* __restrict__ h) {
  const int Di = 4096, LD = 8192;
  int idx = blockIdx.x * 256 + threadIdx.x;
  int d = idx & (Di - 1);
  int l = idx >> 12;
  float4 w = *(const float4*)(cw + (size_t)d * 4);
  float acc = cb[d];
  int ls0 = l - 3;
  if (ls0 >= 0) acc += proj[(size_t)ls0 * LD + d] * w.x;
  if (ls0 + 1 >= 0) acc += proj[(size_t)(ls0 + 1) * LD + d] * w.y;
  if (ls0 + 2 >= 0) acc += proj[(size_t)(ls0 + 2) * LD + d] * w.z;
  acc += proj[(size_t)l * LD + d] * w.w;
  h[idx] = f2bf(acc * fast_sig(acc));
}

// three rmsnorms over the 160-wide ssm rows: dt[128]->bf16, B[16], C[16]
__global__ __launch_bounds__(64)
void ssm_norm_k(const float* __restrict__ ssm, const float* __restrict__ dtw,
                const float* __restrict__ bw, const float* __restrict__ cw,
                u16* __restrict__ dtn, float* __restrict__ Bn,
                float* __restrict__ Cn) {
  int l = blockIdx.x;
  int lane = threadIdx.x;
  const float* r = ssm + (size_t)l * 160;
  float d0 = r[lane];
  float d1 = r[lane + 64];
  float bv = (lane < 16) ? r[128 + lane] : 0.f;
  float cv = (lane < 16) ? r[144 + lane] : 0.f;
  float sd = d0 * d0 + d1 * d1;
  float sb = bv * bv;
  float sc = cv * cv;
#pragma unroll
  for (int m = 32; m > 0; m >>= 1) {
    sd += __shfl_xor(sd, m, 64);
    sb += __shfl_xor(sb, m, 64);
    sc += __shfl_xor(sc, m, 64);
  }
  float scd = rsqrtf(sd * (1.f / 128.f) + 1e-6f);
  float scb = rsqrtf(sb * (1.f / 16.f) + 1e-6f);
  float scc = rsqrtf(sc * (1.f / 16.f) + 1e-6f);
  dtn[(size_t)l * 128 + lane] = f2bf(d0 * scd * dtw[lane]);
  dtn[(size_t)l * 128 + lane + 64] = f2bf(d1 * scd * dtw[lane + 64]);
  if (lane < 16) {
    Bn[(size_t)l * 16 + lane] = bv * scb * bw[lane];
    Cn[(size_t)l * 16 + lane] = cv * scc * cw[lane];
  }
}

// ---------------------------------------------------------------------------
// Chunked parallel scan over L=1024: NCH chunks of CHL.
// Thread = (d, chunk); n=0..15 held in registers (s[16], a[16]).
#define NCH 32
#define CHL 32

// Phase 1: local scan -> carryA = exp(a*sum(del)) (= prod dA), carryS = s_end
__global__ __launch_bounds__(256)
void scan_p1(const float* __restrict__ dpre, const float* __restrict__ dtb,
             const u16* __restrict__ h, const float* __restrict__ Bn,
             const float* __restrict__ Amat,
             float* __restrict__ carryA, float* __restrict__ carryS) {
  const int Di = 4096;
  int chunk = blockIdx.x & (NCH - 1);
  int d = (blockIdx.x >> 5) * 256 + threadIdx.x;
  __shared__ float Bs[CHL * 16];
  for (int i = threadIdx.x; i < CHL * 16; i += 256)
    Bs[i] = Bn[(size_t)chunk * CHL * 16 + i];
  __syncthreads();
  float a[16];
#pragma unroll
  for (int q = 0; q < 4; ++q)
    *(float4*)&a[q * 4] = *(const float4*)(Amat + (size_t)d * 16 + q * 4);
  float bias = dtb[d];
  float s[16];
#pragma unroll
  for (int n = 0; n < 16; ++n) s[n] = 0.f;
  float sumdel = 0.f;
  int l0 = chunk * CHL;
#pragma unroll 4
  for (int j = 0; j < CHL; ++j) {
    int l = l0 + j;
    float del = fast_softplus(dpre[(size_t)l * Di + d] + bias);
    float hv = bf2f(h[(size_t)l * Di + d]);
    sumdel += del;
    float c = del * hv;
#pragma unroll
    for (int n = 0; n < 16; ++n) {
      float dA = __expf(del * a[n]);
      s[n] = dA * s[n] + c * Bs[j * 16 + n];
    }
  }
  size_t base = (size_t)chunk * 65536 + (size_t)d * 16;
#pragma unroll
  for (int n = 0; n < 16; ++n) {
    carryA[base + n] = __expf(sumdel * a[n]);
    carryS[base + n] = s[n];
  }
}

// Phase 2: per (d,n) pair, sequential combine over chunks; carryS <- carry-IN.
__global__ __launch_bounds__(256)
void scan_p2(const float* __restrict__ carryA, float* __restrict__ carryS) {
  int p = blockIdx.x * 256 + threadIdx.x;
  float cin = 0.f;
#pragma unroll
  for (int c = 0; c < NCH; ++c) {
    float av = carryA[(size_t)c * 65536 + p];
    float sv = carryS[(size_t)c * 65536 + p];
    float nx = av * cin + sv;
    carryS[(size_t)c * 65536 + p] = cin;
    cin = nx;
  }
}

// Phase 3: local scan with carry-in; fused y = (s.C + h*D)*silu(gate) -> bf16
__global__ __launch_bounds__(256)
void scan_p3(const float* __restrict__ dpre, const float* __restrict__ dtb,
             const u16* __restrict__ h, const float* __restrict__ Bn,
             const float* __restrict__ Cn, const float* __restrict__ Amat,
             const float* __restrict__ Dw, const float* __restrict__ proj,
             const float* __restrict__ carryS, u16* __restrict__ y) {
  const int Di = 4096;
  int chunk = blockIdx.x & (NCH - 1);
  int d = (blockIdx.x >> 5) * 256 + threadIdx.x;
  __shared__ float Bs[CHL * 16];
  __shared__ float Cs[CHL * 16];
  for (int i = threadIdx.x; i < CHL * 16; i += 256) {
    Bs[i] = Bn[(size_t)chunk * CHL * 16 + i];
    Cs[i] = Cn[(size_t)chunk * CHL * 16 + i];
  }
  __syncthreads();
  float a[16];
#pragma unroll
  for (int q = 0; q < 4; ++q)
    *(float4*)&a[q * 4] = *(const float4*)(Amat + (size_t)d * 16 + q * 4);
  float bias = dtb[d];
  float Dd = Dw[d];
  float s[16];
  size_t base = (size_t)chunk * 65536 + (size_t)d * 16;
#pragma unroll
  for (int q = 0; q < 4; ++q)
    *(float4*)&s[q * 4] = *(const float4*)(carryS + base + q * 4);
  int l0 = chunk * CHL;
#pragma unroll 2
  for (int j = 0; j < CHL; ++j) {
    int l = l0 + j;
    float del = fast_softplus(dpre[(size_t)l * Di + d] + bias);
    float hv = bf2f(h[(size_t)l * Di + d]);
    float c = del * hv;
    float p = 0.f;
#pragma unroll
    for (int n = 0; n < 16; ++n) {
      float dA = __expf(del * a[n]);
      s[n] = dA * s[n] + c * Bs[j * 16 + n];
      p += s[n] * Cs[j * 16 + n];
    }
    float g = proj[(size_t)l * 8192 + 4096 + d];
    float yv = p + hv * Dd;
    y[(size_t)l * Di + d] = f2bf(yv * g * fast_sig(g));
  }
}

// out += ff
__global__ __launch_bounds__(256)
void add_k(float* __restrict__ out, const float* __restrict__ ff) {
  int i = blockIdx.x * 256 + threadIdx.x;
  float4 a = ((const float4*)out)[i];
  float4 b = ((const float4*)ff)[i];
  a.x += b.x; a.y += b.y; a.z += b.z; a.w += b.w;
  ((float4*)out)[i] = a;
}

// ---------------------------------------------------------------------------
extern "C" void kernel_launch(void* const* d_in, const int* in_sizes, int n_in,
                              void* d_out, int out_size, void* d_ws, size_t ws_size,
                              hipStream_t stream) {
  const float* hidden      = (const float*)d_in[0];
  const float* in_ln_w     = (const float*)d_in[1];
  const float* pre_ff_ln_w = (const float*)d_in[2];
  const float* in_proj_w   = (const float*)d_in[3];
  const float* conv_w      = (const float*)d_in[4];
  const float* conv_b      = (const float*)d_in[5];
  const float* x_proj_w    = (const float*)d_in[6];
  const float* dt_ln_w     = (const float*)d_in[7];
  const float* b_ln_w      = (const float*)d_in[8];
  const float* c_ln_w      = (const float*)d_in[9];
  const float* dt_proj_w   = (const float*)d_in[10];
  const float* dt_proj_b   = (const float*)d_in[11];
  const float* Amat        = (const float*)d_in[12];
  const float* Dw          = (const float*)d_in[13];
  const float* out_proj_w  = (const float*)d_in[14];
  const float* gate_up_w   = (const float*)d_in[15];
  const float* down_w      = (const float*)d_in[16];
  float* out = (float*)d_out;
  float* ws = (float*)d_ws;

  const int L = 1024, H = 2048, Di = 4096, F = 8192;

  // workspace (float-element offsets), peak ~106 MB
  u16*   wbuf   = (u16*)ws;                  // weight slab (bf16)
  // carry buffers live in the weight-slab hole during the scan (dt weights
  // only occupy [0, 262144) float-units then; overwritten again at step 9)
  float* carryA = ws + 2097152;              // NCH x 65536 = 2M floats
  float* carryS = ws + 4194304;              // NCH x 65536 = 2M floats
  float* proj   = ws + 8388608;              // L x 8192 fp32
  float* dpre   = ws + 16777216;             // L x 4096 fp32 (raw dt GEMM out)
  u16*   hbuf   = (u16*)(ws + 20971520);     // L x 4096 bf16
  u16*   xnorm  = (u16*)(ws + 23068672);     // L x 2048 bf16 (dead after step 2)
  float* ssm    = ws + 24117248;             // L x 160 fp32
  u16*   dtn    = (u16*)(ws + 24281088);     // L x 128 bf16
  float* Bn     = ws + 24346624;             // L x 16
  float* Cn     = ws + 24363008;             // L x 16
  u16*   ybuf   = (u16*)(ws + 24379392);     // L x 4096 bf16
  float* mix    = ws + 16777216;             // L x 2048 fp32 (reuse dpre, post-scan)
  u16*   x2     = (u16*)(ws + 18874368);     // L x 2048 bf16 (reuse dpre tail)
  u16*   sg     = (u16*)(ws + 8388608);      // L x 8192 bf16 (reuse proj)
  u16*   x3     = (u16*)(ws + 12582912);     // L x 8192 bf16 (reuse proj)
  float* ff     = ws + 19922944;             // L x 2048 fp32 (hbuf dead by then)

  // 1. x_norm = bf16(rmsnorm(hidden))
  rmsnorm2048_k<<<L, 256, 0, stream>>>(hidden, in_ln_w, xnorm);
  // 2. proj = x_norm @ in_proj_w.T  (N=8192, K=2048)
  f32_to_bf16_k<<<16384, 256, 0, stream>>>(in_proj_w, wbuf, 16777216, 16777216);
  gemm_bf16<0><<<dim3(64, 8), 256, 0, stream>>>(xnorm, wbuf, proj, nullptr, nullptr, L, 8192, 2048);
  // 3. h = bf16(silu(conv(proj[:, :Di]) + conv_b))
  conv_silu_k<<<(L * Di) / 256, 256, 0, stream>>>(proj, conv_w, conv_b, hbuf);
  // 4. ssm = h @ x_proj_w.T  (N=160 padded to 256, K=4096)
  f32_to_bf16_k<<<1024, 256, 0, stream>>>(x_proj_w, wbuf, 1048576, 655360);
  gemm_bf16<0><<<dim3(2, 8), 256, 0, stream>>>(hbuf, wbuf, ssm, nullptr, nullptr, L, 160, 4096);
  // 5. split rmsnorms
  ssm_norm_k<<<L, 64, 0, stream>>>(ssm, dt_ln_w, b_ln_w, c_ln_w, dtn, Bn, Cn);
  // 6. delta_pre = dtn @ dt_proj_w.T  (N=4096, K=128)
  f32_to_bf16_k<<<512, 256, 0, stream>>>(dt_proj_w, wbuf, 524288, 524288);
  gemm_bf16<0><<<dim3(32, 8), 256, 0, stream>>>(dtn, wbuf, dpre, nullptr, nullptr, L, 4096, 128);
  // 7-8. chunked scan (softplus fused, n-in-registers) -> ybuf (bf16)
  scan_p1<<<16 * NCH, 256, 0, stream>>>(dpre, dt_proj_b, hbuf, Bn, Amat, carryA, carryS);
  scan_p2<<<256, 256, 0, stream>>>(carryA, carryS);
  scan_p3<<<16 * NCH, 256, 0, stream>>>(dpre, dt_proj_b, hbuf, Bn, Cn, Amat, Dw, proj, carryS, ybuf);
  // 9. mix = y @ out_proj_w.T  (N=2048, K=4096)
  f32_to_bf16_k<<<8192, 256, 0, stream>>>(out_proj_w, wbuf, 8388608, 8388608);
  gemm_bf16<0><<<dim3(16, 8), 256, 0, stream>>>(ybuf, wbuf, mix, nullptr, nullptr, L, 2048, 4096);
  // 10. residual(out) = hidden + mix ; x2 = bf16(rmsnorm(residual))
  add_rmsnorm_k<<<L, 256, 0, stream>>>(hidden, mix, pre_ff_ln_w, out, x2);
  // 11a. sg = bf16(silu(x2 @ gate_w.T))  (N=8192, K=2048)
  f32_to_bf16_k<<<16384, 256, 0, stream>>>(gate_up_w, wbuf, 16777216, 16777216);
  gemm_bf16<1><<<dim3(64, 8), 256, 0, stream>>>(x2, wbuf, nullptr, sg, nullptr, L, 8192, 2048);
  // 11b. x3 = bf16((x2 @ up_w.T) * sg)
  f32_to_bf16_k<<<16384, 256, 0, stream>>>(gate_up_w + 16777216, wbuf, 16777216, 16777216);
  gemm_bf16<2><<<dim3(64, 8), 256, 0, stream>>>(x2, wbuf, nullptr, x3, sg, L, 8192, 2048);
  // 13. ff = x3 @ down_w.T  (N=2048, K=8192)
  f32_to_bf16_k<<<16384, 256, 0, stream>>>(down_w, wbuf, 16777216, 16777216);
  gemm_bf16<0><<<dim3(16, 8), 256, 0, stream>>>(x3, wbuf, ff, nullptr, nullptr, L, 2048, 8192);
  // 14. out += ff
  add_k<<<(L * H / 4) / 256, 256, 0, stream>>>(out, ff);
}

// Round 5
// 726.563 us; speedup vs baseline: 4.3854x; 1.2881x over previous
//
#include <hip/hip_runtime.h>
#include <math.h>

typedef unsigned short u16;
typedef __bf16 bf16x8 __attribute__((ext_vector_type(8)));
typedef short s16x8 __attribute__((ext_vector_type(8)));
typedef short s16x4 __attribute__((ext_vector_type(4)));
typedef float f32x4 __attribute__((ext_vector_type(4)));

__device__ __forceinline__ u16 f2bf(float f) {
  union { float f; unsigned u; } v; v.f = f;
  unsigned u = v.u;
  unsigned r = u + 0x7fffu + ((u >> 16) & 1u);
  return (u16)(r >> 16);
}
__device__ __forceinline__ float bf2f(u16 h) {
  union { unsigned u; float f; } v; v.u = ((unsigned)h) << 16;
  return v.f;
}
__device__ __forceinline__ float fast_softplus(float x) {
  return (x > 20.f) ? x : __logf(1.f + __expf(x));
}
__device__ __forceinline__ float fast_sig(float x) {
  return __builtin_amdgcn_rcpf(1.f + __expf(-x));
}

__device__ __forceinline__ void gld_lds16(const u16* g, u16* l) {
  __builtin_amdgcn_global_load_lds(
      (const __attribute__((address_space(1))) unsigned int*)g,
      (__attribute__((address_space(3))) unsigned int*)l, 16, 0, 0);
}

// ---------------------------------------------------------------------------
// fp32 -> bf16 weight conversion, zero-pads [n_valid, n)
__global__ __launch_bounds__(256)
void f32_to_bf16_k(const float* __restrict__ src, u16* __restrict__ dst,
                   int n, int n_valid) {
  int i = (blockIdx.x * 256 + threadIdx.x) * 4;
  if (i >= n) return;
  s16x4 o;
  if (i + 3 < n_valid) {
    float4 v = *(const float4*)(src + i);
    o[0] = (short)f2bf(v.x); o[1] = (short)f2bf(v.y);
    o[2] = (short)f2bf(v.z); o[3] = (short)f2bf(v.w);
  } else {
    o[0] = 0; o[1] = 0; o[2] = 0; o[3] = 0;
  }
  *(s16x4*)(dst + i) = o;
}

// ---------------------------------------------------------------------------
// GEMM v2: C[M,N] = A[M,K](bf16) @ B[N,K](bf16)^T
// BM=64, BK=64, BN template {64,128}. XOR-swizzled LDS (slot = chunk ^ (row&7))
// applied on the DMA *source* address and the fragment read address.
// MODE 0: C fp32.  MODE 1: Cb = bf16(silu(c)).  MODE 2: Cb = bf16(c*aux).
template <int BN, int MODE>
__global__ __launch_bounds__(256)
void gemm2(const u16* __restrict__ A, const u16* __restrict__ B,
           float* __restrict__ C, u16* __restrict__ Cb,
           const u16* __restrict__ aux, int M, int Nc, int K) {
  constexpr int NJ = BN / 32;    // per-wave n-tiles of 16
  constexpr int BISS = BN / 32;  // B DMA issues (2048 elems each)
  __shared__ __align__(16) u16 As[64 * 64];
  __shared__ __align__(16) u16 Bs[BN * 64];
  const int tid = threadIdx.x;
  const int tm0 = blockIdx.y * 64;
  const int tn0 = blockIdx.x * BN;
  const int wave = tid >> 6;
  const int lane = tid & 63;
  const int wm = (wave >> 1) * 32;
  const int wn = (wave & 1) * (BN / 2);
  const int frow = lane & 15;
  const int fc = lane >> 4;      // k-chunk (of 8 elems) within 32-wide kstep
  const int rmask = frow & 7;    // lane-constant read swizzle

  // DMA mapping: thread stages LDS slot (row=tid>>3 (+32/issue), chunk=tid&7);
  // source global chunk = chunk ^ (row&7)  (row&7 invariant across issues)
  const int r0 = tid >> 3;
  const int csw = (((tid & 7) ^ (r0 & 7)) << 3);
  const u16* gA = A + (size_t)(tm0 + r0) * K + csw;
  const u16* gB = B + (size_t)(tn0 + r0) * K + csw;
  u16* lA = &As[tid * 8];
  u16* lB = &Bs[tid * 8];

  f32x4 acc[2][NJ];
  f32x4 zero = {0.f, 0.f, 0.f, 0.f};
#pragma unroll
  for (int i = 0; i < 2; ++i)
#pragma unroll
    for (int j = 0; j < NJ; ++j) acc[i][j] = zero;

  for (int kt = 0; kt < K; kt += 64) {
    __syncthreads();
    gld_lds16(gA, lA);
    gld_lds16(gA + (size_t)32 * K, lA + 2048);
#pragma unroll
    for (int b = 0; b < BISS; ++b)
      gld_lds16(gB + (size_t)32 * b * K, lB + b * 2048);
    gA += 64; gB += 64;
    __syncthreads();
#pragma unroll
    for (int s = 0; s < 2; ++s) {
      bf16x8 af[2], bfr[NJ];
#pragma unroll
      for (int i = 0; i < 2; ++i) {
        int addr = (wm + i * 16 + frow) * 64 + (((s * 4 + fc) ^ rmask) << 3);
        af[i] = __builtin_bit_cast(bf16x8, *(const s16x8*)&As[addr]);
      }
#pragma unroll
      for (int j = 0; j < NJ; ++j) {
        int addr = (wn + j * 16 + frow) * 64 + (((s * 4 + fc) ^ rmask) << 3);
        bfr[j] = __builtin_bit_cast(bf16x8, *(const s16x8*)&Bs[addr]);
      }
#pragma unroll
      for (int i = 0; i < 2; ++i)
#pragma unroll
        for (int j = 0; j < NJ; ++j)
          acc[i][j] = __builtin_amdgcn_mfma_f32_16x16x32_bf16(af[i], bfr[j], acc[i][j], 0, 0, 0);
    }
  }
  const int ccol = lane & 15;
  const int crow = (lane >> 4) * 4;
#pragma unroll
  for (int i = 0; i < 2; ++i) {
#pragma unroll
    for (int j = 0; j < NJ; ++j) {
      int gn = tn0 + wn + j * 16 + ccol;
      if (gn < Nc) {
        size_t base = (size_t)(tm0 + wm + i * 16 + crow) * Nc + gn;
#pragma unroll
        for (int r = 0; r < 4; ++r) {
          float c = acc[i][j][r];
          size_t idx = base + (size_t)r * Nc;
          if (MODE == 0) {
            C[idx] = c;
          } else if (MODE == 1) {
            Cb[idx] = f2bf(c * fast_sig(c));
          } else {
            Cb[idx] = f2bf(c * bf2f(aux[idx]));
          }
        }
      }
    }
  }
}

// ---------------------------------------------------------------------------
__device__ inline float block_reduce_sum_256(float v) {
  __shared__ float red[4];
  int lane = threadIdx.x & 63, wave = threadIdx.x >> 6;
#pragma unroll
  for (int m = 32; m > 0; m >>= 1) v += __shfl_xor(v, m, 64);
  if (lane == 0) red[wave] = v;
  __syncthreads();
  return red[0] + red[1] + red[2] + red[3];
}

// rmsnorm over C=2048 -> bf16 out
__global__ __launch_bounds__(256)
void rmsnorm2048_k(const float* __restrict__ x, const float* __restrict__ w,
                   u16* __restrict__ y) {
  const int C = 2048;
  const int row = blockIdx.x;
  const int t = threadIdx.x;
  const float4* xr = (const float4*)(x + (size_t)row * C);
  float4 v0 = xr[t];
  float4 v1 = xr[t + 256];
  float ss = v0.x * v0.x + v0.y * v0.y + v0.z * v0.z + v0.w * v0.w +
             v1.x * v1.x + v1.y * v1.y + v1.z * v1.z + v1.w * v1.w;
  float tot = block_reduce_sum_256(ss);
  float sc = rsqrtf(tot * (1.0f / C) + 1e-6f);
  const float4* wr = (const float4*)w;
  float4 w0 = wr[t], w1 = wr[t + 256];
  u16* yr = y + (size_t)row * C;
  s16x4 o0, o1;
  o0[0] = (short)f2bf(v0.x * sc * w0.x); o0[1] = (short)f2bf(v0.y * sc * w0.y);
  o0[2] = (short)f2bf(v0.z * sc * w0.z); o0[3] = (short)f2bf(v0.w * sc * w0.w);
  o1[0] = (short)f2bf(v1.x * sc * w1.x); o1[1] = (short)f2bf(v1.y * sc * w1.y);
  o1[2] = (short)f2bf(v1.z * sc * w1.z); o1[3] = (short)f2bf(v1.w * sc * w1.w);
  *(s16x4*)(yr + t * 4) = o0;
  *(s16x4*)(yr + 1024 + t * 4) = o1;
}

// residual = a + b (fp32 store), x2 = bf16(rmsnorm(residual)*w)
__global__ __launch_bounds__(256)
void add_rmsnorm_k(const float* __restrict__ a, const float* __restrict__ b,
                   const float* __restrict__ w, float* __restrict__ resid,
                   u16* __restrict__ y) {
  const int C = 2048;
  const int row = blockIdx.x;
  const int t = threadIdx.x;
  const float4* ar = (const float4*)(a + (size_t)row * C);
  const float4* br = (const float4*)(b + (size_t)row * C);
  float4 v0 = ar[t], v1 = ar[t + 256];
  float4 u0 = br[t], u1 = br[t + 256];
  v0.x += u0.x; v0.y += u0.y; v0.z += u0.z; v0.w += u0.w;
  v1.x += u1.x; v1.y += u1.y; v1.z += u1.z; v1.w += u1.w;
  float4* rr = (float4*)(resid + (size_t)row * C);
  rr[t] = v0; rr[t + 256] = v1;
  float ss = v0.x * v0.x + v0.y * v0.y + v0.z * v0.z + v0.w * v0.w +
             v1.x * v1.x + v1.y * v1.y + v1.z * v1.z + v1.w * v1.w;
  float tot = block_reduce_sum_256(ss);
  float sc = rsqrtf(tot * (1.0f / C) + 1e-6f);
  const float4* wr = (const float4*)w;
  float4 w0 = wr[t], w1 = wr[t + 256];
  u16* yr = y + (size_t)row * C;
  s16x4 o0, o1;
  o0[0] = (short)f2bf(v0.x * sc * w0.x); o0[1] = (short)f2bf(v0.y * sc * w0.y);
  o0[2] = (short)f2bf(v0.z * sc * w0.z); o0[3] = (short)f2bf(v0.w * sc * w0.w);
  o1[0] = (short)f2bf(v1.x * sc * w1.x); o1[1] = (short)f2bf(v1.y * sc * w1.y);
  o1[2] = (short)f2bf(v1.z * sc * w1.z); o1[3] = (short)f2bf(v1.w * sc * w1.w);
  *(s16x4*)(yr + t * 4) = o0;
  *(s16x4*)(yr + 1024 + t * 4) = o1;
}

// causal depthwise conv (K=4) + bias + silu -> bf16 h
__global__ __launch_bounds__(256)
void conv_silu_k(const float* __restrict__ proj, const float* __restrict__ cw,
                 const float* __restrict__ cb, u16* __restrict__ h) {
  const int Di = 4096, LD = 8192;
  int idx = blockIdx.x * 256 + threadIdx.x;
  int d = idx & (Di - 1);
  int l = idx >> 12;
  float4 w = *(const float4*)(cw + (size_t)d * 4);
  float acc = cb[d];
  int ls0 = l - 3;
  if (ls0 >= 0) acc += proj[(size_t)ls0 * LD + d] * w.x;
  if (ls0 + 1 >= 0) acc += proj[(size_t)(ls0 + 1) * LD + d] * w.y;
  if (ls0 + 2 >= 0) acc += proj[(size_t)(ls0 + 2) * LD + d] * w.z;
  acc += proj[(size_t)l * LD + d] * w.w;
  h[idx] = f2bf(acc * fast_sig(acc));
}

// three rmsnorms over the 160-wide ssm rows: dt[128]->bf16, B[16], C[16]
__global__ __launch_bounds__(64)
void ssm_norm_k(const float* __restrict__ ssm, const float* __restrict__ dtw,
                const float* __restrict__ bw, const float* __restrict__ cw,
                u16* __restrict__ dtn, float* __restrict__ Bn,
                float* __restrict__ Cn) {
  int l = blockIdx.x;
  int lane = threadIdx.x;
  const float* r = ssm + (size_t)l * 160;
  float d0 = r[lane];
  float d1 = r[lane + 64];
  float bv = (lane < 16) ? r[128 + lane] : 0.f;
  float cv = (lane < 16) ? r[144 + lane] : 0.f;
  float sd = d0 * d0 + d1 * d1;
  float sb = bv * bv;
  float sc = cv * cv;
#pragma unroll
  for (int m = 32; m > 0; m >>= 1) {
    sd += __shfl_xor(sd, m, 64);
    sb += __shfl_xor(sb, m, 64);
    sc += __shfl_xor(sc, m, 64);
  }
  float scd = rsqrtf(sd * (1.f / 128.f) + 1e-6f);
  float scb = rsqrtf(sb * (1.f / 16.f) + 1e-6f);
  float scc = rsqrtf(sc * (1.f / 16.f) + 1e-6f);
  dtn[(size_t)l * 128 + lane] = f2bf(d0 * scd * dtw[lane]);
  dtn[(size_t)l * 128 + lane + 64] = f2bf(d1 * scd * dtw[lane + 64]);
  if (lane < 16) {
    Bn[(size_t)l * 16 + lane] = bv * scb * bw[lane];
    Cn[(size_t)l * 16 + lane] = cv * scc * cw[lane];
  }
}

// ---------------------------------------------------------------------------
// Chunked parallel scan over L=1024: NCH chunks of CHL.
// Thread = (d, chunk); n=0..15 held in registers (s[16], a[16]).
#define NCH 32
#define CHL 32

// Phase 1: local scan -> carryA = exp(a*sum(del)) (= prod dA), carryS = s_end
__global__ __launch_bounds__(256)
void scan_p1(const float* __restrict__ dpre, const float* __restrict__ dtb,
             const u16* __restrict__ h, const float* __restrict__ Bn,
             const float* __restrict__ Amat,
             float* __restrict__ carryA, float* __restrict__ carryS) {
  const int Di = 4096;
  int chunk = blockIdx.x & (NCH - 1);
  int d = (blockIdx.x >> 5) * 256 + threadIdx.x;
  __shared__ float Bs[CHL * 16];
  for (int i = threadIdx.x; i < CHL * 16; i += 256)
    Bs[i] = Bn[(size_t)chunk * CHL * 16 + i];
  __syncthreads();
  float a[16];
#pragma unroll
  for (int q = 0; q < 4; ++q)
    *(float4*)&a[q * 4] = *(const float4*)(Amat + (size_t)d * 16 + q * 4);
  float bias = dtb[d];
  float s[16];
#pragma unroll
  for (int n = 0; n < 16; ++n) s[n] = 0.f;
  float sumdel = 0.f;
  int l0 = chunk * CHL;
#pragma unroll 4
  for (int j = 0; j < CHL; ++j) {
    int l = l0 + j;
    float del = fast_softplus(dpre[(size_t)l * Di + d] + bias);
    float hv = bf2f(h[(size_t)l * Di + d]);
    sumdel += del;
    float c = del * hv;
#pragma unroll
    for (int n = 0; n < 16; ++n) {
      float dA = __expf(del * a[n]);
      s[n] = dA * s[n] + c * Bs[j * 16 + n];
    }
  }
  size_t base = (size_t)chunk * 65536 + (size_t)d * 16;
#pragma unroll
  for (int n = 0; n < 16; ++n) {
    carryA[base + n] = __expf(sumdel * a[n]);
    carryS[base + n] = s[n];
  }
}

// Phase 2: per (d,n) pair, sequential combine over chunks; carryS <- carry-IN.
__global__ __launch_bounds__(256)
void scan_p2(const float* __restrict__ carryA, float* __restrict__ carryS) {
  int p = blockIdx.x * 256 + threadIdx.x;
  float cin = 0.f;
#pragma unroll
  for (int c = 0; c < NCH; ++c) {
    float av = carryA[(size_t)c * 65536 + p];
    float sv = carryS[(size_t)c * 65536 + p];
    float nx = av * cin + sv;
    carryS[(size_t)c * 65536 + p] = cin;
    cin = nx;
  }
}

// Phase 3: local scan with carry-in; fused y = (s.C + h*D)*silu(gate) -> bf16
__global__ __launch_bounds__(256)
void scan_p3(const float* __restrict__ dpre, const float* __restrict__ dtb,
             const u16* __restrict__ h, const float* __restrict__ Bn,
             const float* __restrict__ Cn, const float* __restrict__ Amat,
             const float* __restrict__ Dw, const float* __restrict__ proj,
             const float* __restrict__ carryS, u16* __restrict__ y) {
  const int Di = 4096;
  int chunk = blockIdx.x & (NCH - 1);
  int d = (blockIdx.x >> 5) * 256 + threadIdx.x;
  __shared__ float Bs[CHL * 16];
  __shared__ float Cs[CHL * 16];
  for (int i = threadIdx.x; i < CHL * 16; i += 256) {
    Bs[i] = Bn[(size_t)chunk * CHL * 16 + i];
    Cs[i] = Cn[(size_t)chunk * CHL * 16 + i];
  }
  __syncthreads();
  float a[16];
#pragma unroll
  for (int q = 0; q < 4; ++q)
    *(float4*)&a[q * 4] = *(const float4*)(Amat + (size_t)d * 16 + q * 4);
  float bias = dtb[d];
  float Dd = Dw[d];
  float s[16];
  size_t base = (size_t)chunk * 65536 + (size_t)d * 16;
#pragma unroll
  for (int q = 0; q < 4; ++q)
    *(float4*)&s[q * 4] = *(const float4*)(carryS + base + q * 4);
  int l0 = chunk * CHL;
#pragma unroll 2
  for (int j = 0; j < CHL; ++j) {
    int l = l0 + j;
    float del = fast_softplus(dpre[(size_t)l * Di + d] + bias);
    float hv = bf2f(h[(size_t)l * Di + d]);
    float c = del * hv;
    float p = 0.f;
#pragma unroll
    for (int n = 0; n < 16; ++n) {
      float dA = __expf(del * a[n]);
      s[n] = dA * s[n] + c * Bs[j * 16 + n];
      p += s[n] * Cs[j * 16 + n];
    }
    float g = proj[(size_t)l * 8192 + 4096 + d];
    float yv = p + hv * Dd;
    y[(size_t)l * Di + d] = f2bf(yv * g * fast_sig(g));
  }
}

// out += ff
__global__ __launch_bounds__(256)
void add_k(float* __restrict__ out, const float* __restrict__ ff) {
  int i = blockIdx.x * 256 + threadIdx.x;
  float4 a = ((const float4*)out)[i];
  float4 b = ((const float4*)ff)[i];
  a.x += b.x; a.y += b.y; a.z += b.z; a.w += b.w;
  ((float4*)out)[i] = a;
}

// ---------------------------------------------------------------------------
extern "C" void kernel_launch(void* const* d_in, const int* in_sizes, int n_in,
                              void* d_out, int out_size, void* d_ws, size_t ws_size,
                              hipStream_t stream) {
  const float* hidden      = (const float*)d_in[0];
  const float* in_ln_w     = (const float*)d_in[1];
  const float* pre_ff_ln_w = (const float*)d_in[2];
  const float* in_proj_w   = (const float*)d_in[3];
  const float* conv_w      = (const float*)d_in[4];
  const float* conv_b      = (const float*)d_in[5];
  const float* x_proj_w    = (const float*)d_in[6];
  const float* dt_ln_w     = (const float*)d_in[7];
  const float* b_ln_w      = (const float*)d_in[8];
  const float* c_ln_w      = (const float*)d_in[9];
  const float* dt_proj_w   = (const float*)d_in[10];
  const float* dt_proj_b   = (const float*)d_in[11];
  const float* Amat        = (const float*)d_in[12];
  const float* Dw          = (const float*)d_in[13];
  const float* out_proj_w  = (const float*)d_in[14];
  const float* gate_up_w   = (const float*)d_in[15];
  const float* down_w      = (const float*)d_in[16];
  float* out = (float*)d_out;
  float* ws = (float*)d_ws;

  const int L = 1024, H = 2048, Di = 4096, F = 8192;

  // workspace (float-element offsets), peak ~106 MB
  u16*   wbuf   = (u16*)ws;                  // weight slab (bf16)
  float* carryA = ws + 2097152;              // NCH x 65536 (in weight-slab hole)
  float* carryS = ws + 4194304;              // NCH x 65536
  float* proj   = ws + 8388608;              // L x 8192 fp32
  float* dpre   = ws + 16777216;             // L x 4096 fp32 (raw dt GEMM out)
  u16*   hbuf   = (u16*)(ws + 20971520);     // L x 4096 bf16
  u16*   xnorm  = (u16*)(ws + 23068672);     // L x 2048 bf16 (dead after step 2)
  float* ssm    = ws + 24117248;             // L x 160 fp32
  u16*   dtn    = (u16*)(ws + 24281088);     // L x 128 bf16
  float* Bn     = ws + 24346624;             // L x 16
  float* Cn     = ws + 24363008;             // L x 16
  u16*   ybuf   = (u16*)(ws + 24379392);     // L x 4096 bf16
  float* mix    = ws + 16777216;             // L x 2048 fp32 (reuse dpre, post-scan)
  u16*   x2     = (u16*)(ws + 18874368);     // L x 2048 bf16 (reuse dpre tail)
  u16*   sg     = (u16*)(ws + 8388608);      // L x 8192 bf16 (reuse proj)
  u16*   x3     = (u16*)(ws + 12582912);     // L x 8192 bf16 (reuse proj)
  float* ff     = ws + 19922944;             // L x 2048 fp32 (hbuf dead by then)

  // 1. x_norm = bf16(rmsnorm(hidden))
  rmsnorm2048_k<<<L, 256, 0, stream>>>(hidden, in_ln_w, xnorm);
  // 2. proj = x_norm @ in_proj_w.T  (N=8192, K=2048)
  f32_to_bf16_k<<<16384, 256, 0, stream>>>(in_proj_w, wbuf, 16777216, 16777216);
  gemm2<128, 0><<<dim3(64, 16), 256, 0, stream>>>(xnorm, wbuf, proj, nullptr, nullptr, L, 8192, 2048);
  // 3. h = bf16(silu(conv(proj[:, :Di]) + conv_b))
  conv_silu_k<<<(L * Di) / 256, 256, 0, stream>>>(proj, conv_w, conv_b, hbuf);
  // 4. ssm = h @ x_proj_w.T  (N=160 padded to 256, K=4096)
  f32_to_bf16_k<<<1024, 256, 0, stream>>>(x_proj_w, wbuf, 1048576, 655360);
  gemm2<64, 0><<<dim3(4, 16), 256, 0, stream>>>(hbuf, wbuf, ssm, nullptr, nullptr, L, 160, 4096);
  // 5. split rmsnorms
  ssm_norm_k<<<L, 64, 0, stream>>>(ssm, dt_ln_w, b_ln_w, c_ln_w, dtn, Bn, Cn);
  // 6. delta_pre = dtn @ dt_proj_w.T  (N=4096, K=128)
  f32_to_bf16_k<<<512, 256, 0, stream>>>(dt_proj_w, wbuf, 524288, 524288);
  gemm2<128, 0><<<dim3(32, 16), 256, 0, stream>>>(dtn, wbuf, dpre, nullptr, nullptr, L, 4096, 128);
  // 7-8. chunked scan (softplus fused, n-in-registers) -> ybuf (bf16)
  scan_p1<<<16 * NCH, 256, 0, stream>>>(dpre, dt_proj_b, hbuf, Bn, Amat, carryA, carryS);
  scan_p2<<<256, 256, 0, stream>>>(carryA, carryS);
  scan_p3<<<16 * NCH, 256, 0, stream>>>(dpre, dt_proj_b, hbuf, Bn, Cn, Amat, Dw, proj, carryS, ybuf);
  // 9. mix = y @ out_proj_w.T  (N=2048, K=4096)
  f32_to_bf16_k<<<8192, 256, 0, stream>>>(out_proj_w, wbuf, 8388608, 8388608);
  gemm2<64, 0><<<dim3(32, 16), 256, 0, stream>>>(ybuf, wbuf, mix, nullptr, nullptr, L, 2048, 4096);
  // 10. residual(out) = hidden + mix ; x2 = bf16(rmsnorm(residual))
  add_rmsnorm_k<<<L, 256, 0, stream>>>(hidden, mix, pre_ff_ln_w, out, x2);
  // 11a. sg = bf16(silu(x2 @ gate_w.T))  (N=8192, K=2048)
  f32_to_bf16_k<<<16384, 256, 0, stream>>>(gate_up_w, wbuf, 16777216, 16777216);
  gemm2<128, 1><<<dim3(64, 16), 256, 0, stream>>>(x2, wbuf, nullptr, sg, nullptr, L, 8192, 2048);
  // 11b. x3 = bf16((x2 @ up_w.T) * sg)
  f32_to_bf16_k<<<16384, 256, 0, stream>>>(gate_up_w + 16777216, wbuf, 16777216, 16777216);
  gemm2<128, 2><<<dim3(64, 16), 256, 0, stream>>>(x2, wbuf, nullptr, x3, sg, L, 8192, 2048);
  // 13. ff = x3 @ down_w.T  (N=2048, K=8192)
  f32_to_bf16_k<<<16384, 256, 0, stream>>>(down_w, wbuf, 16777216, 16777216);
  gemm2<64, 0><<<dim3(32, 16), 256, 0, stream>>>(x3, wbuf, ff, nullptr, nullptr, L, 2048, 8192);
  // 14. out += ff
  add_k<<<(L * H / 4) / 256, 256, 0, stream>>>(out, ff);
}